// Round 14
// baseline (239.376 us; speedup 1.0000x reference)
//
#include <hip/hip_runtime.h>
#include <hip/hip_fp16.h>
#include <math.h>

#define NH 8
#define NT 4
#define NR 4
#define MAXLEN 240

typedef __attribute__((ext_vector_type(8))) short bf16x8;
typedef __attribute__((ext_vector_type(4))) float f32x4;
typedef __attribute__((ext_vector_type(2))) float f32x2;

#if defined(__has_builtin)
#if __has_builtin(__builtin_amdgcn_cvt_pk_f32_fp8) && __has_builtin(__builtin_amdgcn_cvt_pk_fp8_f32)
#define HAS_HW_FP8 1
#endif
#endif

__device__ __forceinline__ unsigned short f2bf(float x) {
    unsigned u = __float_as_uint(x);
    u += 0x7fffu + ((u >> 16) & 1u);
    return (unsigned short)(u >> 16);
}
__device__ __forceinline__ float bflo(unsigned u) { return __uint_as_float(u << 16); }
__device__ __forceinline__ float bfhi(unsigned u) { return __uint_as_float(u & 0xffff0000u); }
__device__ __forceinline__ unsigned pack2(float a, float b) {
    return (unsigned)f2bf(a) | ((unsigned)f2bf(b) << 16);
}

// ---- fp8 e4m3 codec (true scale) ----
__device__ __forceinline__ void fp8x4_dec(unsigned w, float* f) {
#ifdef HAS_HW_FP8
    f32x2 lo = __builtin_amdgcn_cvt_pk_f32_fp8(w, false);
    f32x2 hi = __builtin_amdgcn_cvt_pk_f32_fp8(w, true);
    f[0] = lo[0]; f[1] = lo[1]; f[2] = hi[0]; f[3] = hi[1];
#else
    unsigned ev = w & 0x00ff00ffu;
    unsigned od = (w >> 8) & 0x00ff00ffu;
    unsigned he = (((ev << 8) & 0x80008000u) | ((ev << 7) & 0x3f803f80u)) + 0x04000400u;
    unsigned ho = (((od << 8) & 0x80008000u) | ((od << 7) & 0x3f803f80u)) + 0x04000400u;
    __half2 h2e = *reinterpret_cast<__half2*>(&he);
    __half2 h2o = *reinterpret_cast<__half2*>(&ho);
    float2 fe = __half22float2(h2e);
    float2 fo = __half22float2(h2o);
    f[0] = fe.x; f[1] = fo.x; f[2] = fe.y; f[3] = fo.y;
#endif
}
__device__ __forceinline__ unsigned fp8x2_enc(float a, float b) {
#ifdef HAS_HW_FP8
    return (unsigned)__builtin_amdgcn_cvt_pk_fp8_f32(a, b, 0, false) & 0xffffu;
#else
    auto enc1 = [](float x) -> unsigned {
        float cl = fminf(fmaxf(x, -448.f), 448.f);
        __half h = __float2half(cl * 0.00390625f);
        unsigned short hr = *reinterpret_cast<unsigned short*>(&h);
        unsigned short rnd = (unsigned short)((hr & 0x7fff) + 0x3f + ((hr >> 7) & 1));
        return (unsigned)(((rnd >> 7) & 0x7f) | ((hr >> 8) & 0x80));
    };
    return enc1(a) | (enc1(b) << 8);
#endif
}

__global__ void zero_kernel(int* deg, int* cursor, int* dcnt, int* dcur, int N) {
    int i = blockIdx.x * blockDim.x + threadIdx.x;
    int stride = gridDim.x * blockDim.x;
    if (i < 256) { dcnt[i] = 0; dcur[i] = 0; }
    for (int j = i; j < N; j += stride) { deg[j] = 0; cursor[j] = 0; }
}

__global__ void deg_kernel(const int* __restrict__ ei, int* __restrict__ deg, int E) {
    int i = blockIdx.x * blockDim.x + threadIdx.x;
    int stride = gridDim.x * blockDim.x;
    for (int e = i; e < E; e += stride) atomicAdd(&deg[ei[E + e]], 1);
}

// 256-bucket key: type*64 + (63 - min(deg,63))
__global__ __launch_bounds__(256) void histA(const int* __restrict__ ntype,
                                             const int* __restrict__ deg,
                                             int* __restrict__ dcnt, int N) {
    __shared__ int h[256];
    int tid = threadIdx.x;
    h[tid] = 0;
    __syncthreads();
    int i = blockIdx.x * 256 + tid;
    if (i < N) atomicAdd(&h[ntype[i] * 64 + 63 - min(deg[i], 63)], 1);
    __syncthreads();
    if (h[tid]) atomicAdd(&dcnt[tid], h[tid]);
}

__global__ __launch_bounds__(256) void histB(const int* __restrict__ dcnt,
                                             int* __restrict__ dbase) {
    __shared__ int tmp[256];
    int v = dcnt[threadIdx.x];
    tmp[threadIdx.x] = v;
    __syncthreads();
    #pragma unroll
    for (int off = 1; off < 256; off <<= 1) {
        int t = threadIdx.x >= off ? tmp[threadIdx.x - off] : 0;
        __syncthreads();
        tmp[threadIdx.x] += t;
        __syncthreads();
    }
    dbase[threadIdx.x] = tmp[threadIdx.x] - v;
}

__global__ __launch_bounds__(256) void histC(const int* __restrict__ ntype,
                                             const int* __restrict__ deg,
                                             const int* __restrict__ dbase, int* __restrict__ dcur,
                                             int* __restrict__ nlist, int* __restrict__ spos,
                                             int* __restrict__ stype_s, int* __restrict__ deg_s,
                                             int N) {
    __shared__ int h[256];
    __shared__ int bb[256];
    __shared__ int cur[256];
    int tid = threadIdx.x;
    h[tid] = 0; cur[tid] = 0;
    __syncthreads();
    int i = blockIdx.x * 256 + tid;
    int b = -1, t = 0, dg = 0;
    if (i < N) {
        t = ntype[i]; dg = deg[i];
        b = t * 64 + 63 - min(dg, 63);
        atomicAdd(&h[b], 1);
    }
    __syncthreads();
    if (h[tid]) bb[tid] = atomicAdd(&dcur[tid], h[tid]);
    __syncthreads();
    if (i < N) {
        int r = atomicAdd(&cur[b], 1);
        int p = dbase[b] + bb[b] + r;
        nlist[p] = i;
        spos[i] = p;
        stype_s[p] = t;
        deg_s[p] = dg;
    }
}

__global__ __launch_bounds__(256) void scanA(const int* __restrict__ deg, int* __restrict__ excl,
                                             int* __restrict__ bsum, int N) {
    __shared__ int tmp[256];
    int i = blockIdx.x * 256 + threadIdx.x;
    int v = i < N ? deg[i] : 0;
    tmp[threadIdx.x] = v;
    __syncthreads();
    #pragma unroll
    for (int off = 1; off < 256; off <<= 1) {
        int t = threadIdx.x >= off ? tmp[threadIdx.x - off] : 0;
        __syncthreads();
        tmp[threadIdx.x] += t;
        __syncthreads();
    }
    if (i < N) excl[i] = tmp[threadIdx.x] - v;
    if (threadIdx.x == 255) bsum[blockIdx.x] = tmp[255];
}

__global__ __launch_bounds__(256) void scanB(int* __restrict__ bsum, int nb) {
    __shared__ int tmp[256];
    int v = threadIdx.x < nb ? bsum[threadIdx.x] : 0;
    tmp[threadIdx.x] = v;
    __syncthreads();
    #pragma unroll
    for (int off = 1; off < 256; off <<= 1) {
        int t = threadIdx.x >= off ? tmp[threadIdx.x - off] : 0;
        __syncthreads();
        tmp[threadIdx.x] += t;
        __syncthreads();
    }
    if (threadIdx.x < nb) bsum[threadIdx.x] = tmp[threadIdx.x] - v;
}

__global__ void scanC(const int* __restrict__ excl, const int* __restrict__ bsum,
                      int* __restrict__ row_start, int N) {
    int i = blockIdx.x * blockDim.x + threadIdx.x;
    if (i < N) row_start[i] = excl[i] + bsum[i >> 8];
}

// ebuf entry: sps(17) | r(2)@17 | tm(8)@19 | st(2)@27
__global__ void scatter_kernel(const int* __restrict__ ei, const int* __restrict__ etype,
                               const int* __restrict__ etime, const int* __restrict__ spos,
                               const int* __restrict__ dbase,
                               const int* __restrict__ row_start, int* __restrict__ cursor,
                               unsigned* __restrict__ ebuf, int E) {
    int tb1 = dbase[64], tb2 = dbase[128], tb3 = dbase[192];
    int i = blockIdx.x * blockDim.x + threadIdx.x;
    int stride = gridDim.x * blockDim.x;
    for (int e = i; e < E; e += stride) {
        int sps = spos[ei[e]];
        int spt = spos[ei[E + e]];
        int st = (sps >= tb1) + (sps >= tb2) + (sps >= tb3);
        int pos = atomicAdd(&cursor[spt], 1);
        ebuf[row_start[spt] + pos] =
            (unsigned)sps | ((unsigned)etype[e] << 17) | ((unsigned)etime[e] << 19) | ((unsigned)st << 27);
    }
}

// Fused RTE tables -> combined fp8 table rtec8[(st*4+r)*240+tm][256B]:
// chunk c: bytes[c*16..+8) = vmrte dims 8c..8c+8, bytes[c*16+8..+16) = krte dims.
__global__ __launch_bounds__(128) void rte_tables(
    const float* __restrict__ rte_W, const float* __restrict__ rte_b,
    const float* __restrict__ Wk, const float* __restrict__ Wv,
    const float* __restrict__ rel_msg,
    unsigned char* __restrict__ rtec8) {
    int m = blockIdx.x, t = blockIdx.y, d = threadIdx.x;
    __shared__ float emb[128];
    __shared__ float sr[128];
    __shared__ float vr[128];
    int j2 = d & ~1;
    float div = expf((float)j2 * (-9.210340371976184f / 128.f));
    float ang = (float)m * div;
    emb[d] = ((d & 1) ? cosf(ang) : sinf(ang)) * 0.08838834764831845f;
    __syncthreads();
    float ro = rte_b[d];
    #pragma unroll 8
    for (int i = 0; i < 128; ++i) ro += emb[i] * rte_W[i * 128 + d];
    sr[d] = ro;
    __syncthreads();
    float ak = 0.f, av = 0.f;
    for (int i = 0; i < 128; ++i) {
        float rv = sr[i];
        ak += rv * Wk[(t * 128 + i) * 128 + d];
        av += rv * Wv[(t * 128 + i) * 128 + d];
    }
    unsigned char kb = (unsigned char)(fp8x2_enc(fminf(fmaxf(ak, -440.f), 440.f), 0.f) & 0xff);
    int koff = (d >> 3) * 16 + 8 + (d & 7);
    #pragma unroll
    for (int r = 0; r < NR; ++r)
        rtec8[(size_t)((t * 4 + r) * MAXLEN + m) * 256 + koff] = kb;
    vr[d] = av;
    __syncthreads();
    int h = d >> 4, dd = d & 15;
    int voff = (d >> 3) * 16 + (d & 7);
    for (int r = 0; r < NR; ++r) {
        float acc = 0.f;
        #pragma unroll
        for (int k = 0; k < 16; ++k)
            acc += vr[h * 16 + k] * rel_msg[((r * NH + h) * 16 + k) * 16 + dd];
        unsigned char vb = (unsigned char)(fp8x2_enc(fminf(fmaxf(acc, -440.f), 440.f), 0.f) & 0xff);
        rtec8[(size_t)((t * 4 + r) * MAXLEN + m) * 256 + voff] = vb;
    }
}

// Fold rel transforms into weights (true scale).
__global__ __launch_bounds__(256) void pack_w9(
    const float* __restrict__ Wk, const float* __restrict__ Wq,
    const float* __restrict__ Wv, const float* __restrict__ Wa,
    const float* __restrict__ bk, const float* __restrict__ bq,
    const float* __restrict__ bv, const float* __restrict__ ba,
    const float* __restrict__ rel_att, const float* __restrict__ rel_msg,
    const float* __restrict__ rel_pri,
    short* __restrict__ PW2, float* __restrict__ PB) {
    if (blockIdx.x >= 320) {
        int bidx = (blockIdx.x - 320) * 256 + threadIdx.x;
        int col = bidx & 127, t = (bidx >> 7) & 3, set = bidx >> 9;
        int h = col >> 4, kk = col & 15;
        float val;
        if (set == 0) val = bk[t * 128 + col];
        else if (set == 9) val = ba[t * 128 + col];
        else if (set <= 4) {
            int r = set - 1;
            float pri = rel_pri[r * NH + h] * 0.25f;
            float acc = 0.f;
            #pragma unroll
            for (int dp = 0; dp < 16; ++dp)
                acc += bq[t * 128 + h * 16 + dp] * rel_att[((r * NH + h) * 16 + kk) * 16 + dp];
            val = acc * pri;
        } else {
            int r = set - 5;
            float acc = 0.f;
            #pragma unroll
            for (int kp = 0; kp < 16; ++kp)
                acc += bv[t * 128 + h * 16 + kp] * rel_msg[((r * NH + h) * 16 + kp) * 16 + kk];
            val = acc;
        }
        PB[bidx] = val;
        return;
    }
    int idx = blockIdx.x * 256 + threadIdx.x;
    int lane = idx & 63;
    int ks = (idx >> 6) & 3;
    int ctg = (idx >> 8) & 7;
    int t = (idx >> 11) & 3;
    int set = idx >> 13;
    int col = ctg * 16 + (lane & 15);
    int k0 = ks * 32 + (lane >> 4) * 8;
    int h = col >> 4, kk = col & 15;
    unsigned short o[8];
    if (set == 0 || set == 9) {
        const float* W = (set == 0 ? Wk : Wa) + t * 16384;
        #pragma unroll
        for (int j = 0; j < 8; ++j) o[j] = f2bf(W[(k0 + j) * 128 + col]);
    } else if (set <= 4) {
        int r = set - 1;
        float pri = rel_pri[r * NH + h] * 0.25f;
        float Ar[16];
        #pragma unroll
        for (int dp = 0; dp < 16; ++dp)
            Ar[dp] = rel_att[((r * NH + h) * 16 + kk) * 16 + dp] * pri;
        #pragma unroll
        for (int j = 0; j < 8; ++j) {
            const float* wr = Wq + (size_t)(t * 128 + k0 + j) * 128 + h * 16;
            float acc = 0.f;
            #pragma unroll
            for (int dp = 0; dp < 16; ++dp) acc += wr[dp] * Ar[dp];
            o[j] = f2bf(acc);
        }
    } else {
        int r = set - 5;
        float Mc[16];
        #pragma unroll
        for (int kp = 0; kp < 16; ++kp)
            Mc[kp] = rel_msg[((r * NH + h) * 16 + kp) * 16 + kk];
        #pragma unroll
        for (int j = 0; j < 8; ++j) {
            const float* wr = Wv + (size_t)(t * 128 + k0 + j) * 128 + h * 16;
            float acc = 0.f;
            #pragma unroll
            for (int kp = 0; kp < 16; ++kp) acc += wr[kp] * Mc[kp];
            o[j] = f2bf(acc);
        }
    }
    uint4 pk;
    pk.x = (unsigned)o[0] | ((unsigned)o[1] << 16);
    pk.y = (unsigned)o[2] | ((unsigned)o[3] << 16);
    pk.z = (unsigned)o[4] | ((unsigned)o[5] << 16);
    pk.w = (unsigned)o[6] | ((unsigned)o[7] << 16);
    *reinterpret_cast<uint4*>(PW2 + (size_t)idx * 8) = pk;
}

#define S8 144    // fp8 staging row stride (bytes)
#define KST 144   // kn_keep row stride (bytes)

// 32 sorted nodes/tile: MFMA GEMM, ALL 9 output sets fp8.
// Double-buffered staging: 1 barrier per set.
__global__ __launch_bounds__(256, 4) void kqv2(
    const float* __restrict__ x, const int* __restrict__ nlist_,
    const int* __restrict__ stype_s, const short* __restrict__ PW2,
    const float* __restrict__ PB,
    unsigned char* __restrict__ knvm8, unsigned char* __restrict__ qa8, int N) {
    __shared__ short af_l[2][4][64][8];
    __shared__ unsigned char obuf[2][32 * S8];
    __shared__ unsigned char kn_keep[32 * KST];
    __shared__ int st_l[32];
    const int tid = threadIdx.x;
    const int sp0 = blockIdx.x * 32;
    if (tid < 32) {
        int sp = sp0 + tid;
        st_l[tid] = stype_s[sp < N ? sp : N - 1];
    }
    {
        int i = tid >> 3;
        int d0 = (tid & 7) * 16;
        int sp = sp0 + i;
        int nid = nlist_[sp < N ? sp : N - 1];
        const float* xr = x + (size_t)nid * 128 + d0;
        float4 f0 = *reinterpret_cast<const float4*>(xr);
        float4 f1 = *reinterpret_cast<const float4*>(xr + 4);
        float4 f2 = *reinterpret_cast<const float4*>(xr + 8);
        float4 f3 = *reinterpret_cast<const float4*>(xr + 12);
        int m = i >> 4, rr = i & 15;
        int ks = d0 >> 5;
        int sub = (d0 >> 3) & 3;
        uint4 p0, p1;
        p0.x = pack2(f0.x, f0.y); p0.y = pack2(f0.z, f0.w);
        p0.z = pack2(f1.x, f1.y); p0.w = pack2(f1.z, f1.w);
        p1.x = pack2(f2.x, f2.y); p1.y = pack2(f2.z, f2.w);
        p1.z = pack2(f3.x, f3.y); p1.w = pack2(f3.z, f3.w);
        *reinterpret_cast<uint4*>(&af_l[m][ks][sub * 16 + rr][0]) = p0;
        *reinterpret_cast<uint4*>(&af_l[m][ks][(sub + 1) * 16 + rr][0]) = p1;
    }
    __syncthreads();

    const int lane = tid & 63, w = tid >> 6;
    const int col_l = lane & 15, rowg = lane >> 4;
    const int t0 = st_l[0], t1 = st_l[31];

    bf16x8 afr[2][4];
    #pragma unroll
    for (int m = 0; m < 2; ++m)
        #pragma unroll
        for (int ks = 0; ks < 4; ++ks)
            afr[m][ks] = *reinterpret_cast<const bf16x8*>(&af_l[m][ks][lane][0]);

    const int wi = tid >> 3, wseg = tid & 7;
    const int wsp = sp0 + wi;

    for (int set = 0; set < 9; ++set) {
        unsigned char* buf = &obuf[set & 1][0];
        for (int t = t0; t <= t1; ++t) {
            #pragma unroll
            for (int c = 0; c < 2; ++c) {
                int ctg = w + c * 4;
                bf16x8 pf[4];
                #pragma unroll
                for (int ks = 0; ks < 4; ++ks)
                    pf[ks] = *reinterpret_cast<const bf16x8*>(
                        PW2 + ((size_t)((((set * 4 + t) * 8 + ctg) * 4 + ks) * 64 + lane)) * 8);
                float bval = PB[(set * 4 + t) * 128 + ctg * 16 + col_l];
                #pragma unroll
                for (int m = 0; m < 2; ++m) {
                    f32x4 acc = {0.f, 0.f, 0.f, 0.f};
                    #pragma unroll
                    for (int ks = 0; ks < 4; ++ks)
                        acc = __builtin_amdgcn_mfma_f32_16x16x32_bf16(afr[m][ks], pf[ks], acc, 0, 0, 0);
                    float c0 = fminf(fmaxf(acc[0] + bval, -440.f), 440.f);
                    float c1 = fminf(fmaxf(acc[1] + bval, -440.f), 440.f);
                    float c2 = fminf(fmaxf(acc[2] + bval, -440.f), 440.f);
                    float c3 = fminf(fmaxf(acc[3] + bval, -440.f), 440.f);
                    unsigned pA = fp8x2_enc(c0, c1);
                    unsigned pB = fp8x2_enc(c2, c3);
                    unsigned char by[4];
                    by[0] = (unsigned char)(pA & 0xff);
                    by[1] = (unsigned char)((pA >> 8) & 0xff);
                    by[2] = (unsigned char)(pB & 0xff);
                    by[3] = (unsigned char)((pB >> 8) & 0xff);
                    #pragma unroll
                    for (int j = 0; j < 4; ++j) {
                        int i = m * 16 + rowg * 4 + j;
                        if (st_l[i] == t)
                            buf[i * S8 + ctg * 16 + col_l] = by[j];
                    }
                }
            }
        }
        __syncthreads();
        if (set == 0) {
            *reinterpret_cast<uint4*>(&kn_keep[wi * KST + wseg * 16]) =
                *reinterpret_cast<const uint4*>(&buf[wi * S8 + wseg * 16]);
        } else if (set <= 4) {
            if (wsp < N) {
                int r = set - 1;
                *reinterpret_cast<uint4*>(qa8 + (size_t)(wsp * 4 + r) * 128 + wseg * 16) =
                    *reinterpret_cast<const uint4*>(&buf[wi * S8 + wseg * 16]);
            }
        } else {
            if (wsp < N) {
                int r = set - 5;
                unsigned char* dst = knvm8 + (size_t)(wsp * 4 + r) * 256;
                #pragma unroll
                for (int cc = 0; cc < 2; ++cc) {
                    int c = wseg * 2 + cc;
                    uint2 vmc = *reinterpret_cast<const uint2*>(&buf[wi * S8 + c * 8]);
                    uint2 knc = *reinterpret_cast<const uint2*>(&kn_keep[wi * KST + c * 8]);
                    uint4 outv;
                    outv.x = vmc.x; outv.y = vmc.y; outv.z = knc.x; outv.w = knc.y;
                    *reinterpret_cast<uint4*>(dst + c * 16) = outv;
                }
            }
        }
    }
}

// ONE NODE PER WAVE: 4 edge-slots x 16 dim-lanes. Softmax (no max) is
// associative -> slots accumulate independent partials, merged by 2 shuffles.
__global__ __launch_bounds__(256) void fused_edge_attn(
    const unsigned* __restrict__ ebuf, const int* __restrict__ row_start,
    const int* __restrict__ deg_s,
    const unsigned char* __restrict__ knvm8, const unsigned char* __restrict__ rtec8,
    const unsigned char* __restrict__ qa8,
    unsigned short* __restrict__ aggr_bf, int N) {
    int sp = blockIdx.x * 4 + (threadIdx.x >> 6);
    if (sp >= N) return;
    int lane = threadIdx.x & 63;
    int slot = lane >> 4;
    int l16 = lane & 15;
    uint4 q[4];
    #pragma unroll
    for (int r = 0; r < 4; ++r) {
        uint2 qv = *reinterpret_cast<const uint2*>(qa8 + (size_t)(sp * 4 + r) * 128 + l16 * 8);
        float f[8];
        fp8x4_dec(qv.x, f); fp8x4_dec(qv.y, f + 4);
        q[r].x = pack2(f[0], f[1]); q[r].y = pack2(f[2], f[3]);
        q[r].z = pack2(f[4], f[5]); q[r].w = pack2(f[6], f[7]);
    }
    int start = row_start[sp], cnt = deg_s[sp];
    float den = 0.f;
    float acc[8] = {0.f, 0.f, 0.f, 0.f, 0.f, 0.f, 0.f, 0.f};
    for (int i = slot; i < cnt; i += 4) {
        unsigned e0 = ebuf[start + i];
        int sps0 = e0 & 0x1ffff, r0 = (e0 >> 17) & 3, tm0 = (e0 >> 19) & 255, st0 = (e0 >> 27) & 3;
        uint4 g1 = *reinterpret_cast<const uint4*>(knvm8 + (size_t)(sps0 * 4 + r0) * 256 + l16 * 16);
        uint4 g2 = *reinterpret_cast<const uint4*>(rtec8 + (size_t)((st0 * 4 + r0) * MAXLEN + tm0) * 256 + l16 * 16);
        float mf[8], kf[8], mr[8], kr[8];
        fp8x4_dec(g1.x, mf); fp8x4_dec(g1.y, mf + 4);
        fp8x4_dec(g1.z, kf); fp8x4_dec(g1.w, kf + 4);
        fp8x4_dec(g2.x, mr); fp8x4_dec(g2.y, mr + 4);
        fp8x4_dec(g2.z, kr); fp8x4_dec(g2.w, kr + 4);
        uint4 q0 = q[r0];
        float p = (kf[0] + kr[0]) * bflo(q0.x) + (kf[1] + kr[1]) * bfhi(q0.x)
                + (kf[2] + kr[2]) * bflo(q0.y) + (kf[3] + kr[3]) * bfhi(q0.y)
                + (kf[4] + kr[4]) * bflo(q0.z) + (kf[5] + kr[5]) * bfhi(q0.z)
                + (kf[6] + kr[6]) * bflo(q0.w) + (kf[7] + kr[7]) * bfhi(q0.w);
        // head dot-product: pair lanes (2h, 2h+1) within the slot
        p += __shfl_xor(p, 1);
        float w0 = __expf(p);
        den += w0;
        #pragma unroll
        for (int j = 0; j < 8; ++j)
            acc[j] += w0 * (mf[j] + mr[j]);
    }
    // merge slot partials (whole wave active)
    den += __shfl_xor(den, 16);
    den += __shfl_xor(den, 32);
    #pragma unroll
    for (int j = 0; j < 8; ++j) {
        acc[j] += __shfl_xor(acc[j], 16);
        acc[j] += __shfl_xor(acc[j], 32);
    }
    if (slot == 0) {
        float inv = den > 0.f ? 1.f / den : 0.f;
        uint4 o;
        o.x = pack2(acc[0] * inv, acc[1] * inv);
        o.y = pack2(acc[2] * inv, acc[3] * inv);
        o.z = pack2(acc[4] * inv, acc[5] * inv);
        o.w = pack2(acc[6] * inv, acc[7] * inv);
        *reinterpret_cast<uint4*>(aggr_bf + (size_t)sp * 128 + l16 * 8) = o;
    }
}

// 32 sorted nodes/tile: gelu(aggr bf16) -> MFMA Wa -> skip-blend -> LN -> scatter out
__global__ __launch_bounds__(256, 4) void update_sorted(
    const float* __restrict__ x, const int* __restrict__ nlist_,
    const int* __restrict__ stype_s, const short* __restrict__ PW2,
    const float* __restrict__ PB, const float* __restrict__ gamma,
    const float* __restrict__ beta, const float* __restrict__ skip,
    const unsigned short* __restrict__ aggr_bf, float* __restrict__ out, int N) {
    __shared__ short af_l[2][4][64][8];
    __shared__ float hs[32][128];
    __shared__ int st_l[32];
    __shared__ int nid_l[32];
    const int tid = threadIdx.x;
    const int sp0 = blockIdx.x * 32;
    if (tid < 32) {
        int sp = sp0 + tid;
        int spc = sp < N ? sp : N - 1;
        st_l[tid] = stype_s[spc];
        nid_l[tid] = nlist_[spc];
    }
    {
        int i = tid >> 3;
        int d0 = (tid & 7) * 16;
        int spc = sp0 + i < N ? sp0 + i : N - 1;
        const unsigned short* ar = aggr_bf + (size_t)spc * 128 + d0;
        uint4 v0 = *reinterpret_cast<const uint4*>(ar);
        uint4 v1 = *reinterpret_cast<const uint4*>(ar + 8);
        unsigned vv[8] = {v0.x, v0.y, v0.z, v0.w, v1.x, v1.y, v1.z, v1.w};
        float g[16];
        #pragma unroll
        for (int c = 0; c < 8; ++c) {
            float a0 = bflo(vv[c]), a1 = bfhi(vv[c]);
            g[c * 2 + 0] = 0.5f * a0 * (1.f + erff(a0 * 0.7071067811865476f));
            g[c * 2 + 1] = 0.5f * a1 * (1.f + erff(a1 * 0.7071067811865476f));
        }
        int m = i >> 4, rr = i & 15;
        int ks = d0 >> 5;
        int sub = (d0 >> 3) & 3;
        uint4 p0, p1;
        p0.x = pack2(g[0], g[1]);  p0.y = pack2(g[2], g[3]);
        p0.z = pack2(g[4], g[5]);  p0.w = pack2(g[6], g[7]);
        p1.x = pack2(g[8], g[9]);  p1.y = pack2(g[10], g[11]);
        p1.z = pack2(g[12], g[13]); p1.w = pack2(g[14], g[15]);
        *reinterpret_cast<uint4*>(&af_l[m][ks][sub * 16 + rr][0]) = p0;
        *reinterpret_cast<uint4*>(&af_l[m][ks][(sub + 1) * 16 + rr][0]) = p1;
    }
    __syncthreads();

    const int lane = tid & 63, w = tid >> 6;
    const int col_l = lane & 15, rowg = lane >> 4;
    const int t0 = st_l[0], t1 = st_l[31];

    bf16x8 afr[2][4];
    #pragma unroll
    for (int m = 0; m < 2; ++m)
        #pragma unroll
        for (int ks = 0; ks < 4; ++ks)
            afr[m][ks] = *reinterpret_cast<const bf16x8*>(&af_l[m][ks][lane][0]);

    for (int t = t0; t <= t1; ++t) {
        #pragma unroll
        for (int c = 0; c < 2; ++c) {
            int ctg = w + c * 4;
            bf16x8 pf[4];
            #pragma unroll
            for (int ks = 0; ks < 4; ++ks)
                pf[ks] = *reinterpret_cast<const bf16x8*>(
                    PW2 + ((size_t)((((9 * 4 + t) * 8 + ctg) * 4 + ks) * 64 + lane)) * 8);
            float bval = PB[(9 * 4 + t) * 128 + ctg * 16 + col_l];
            #pragma unroll
            for (int m = 0; m < 2; ++m) {
                f32x4 acc = {0.f, 0.f, 0.f, 0.f};
                #pragma unroll
                for (int ks = 0; ks < 4; ++ks)
                    acc = __builtin_amdgcn_mfma_f32_16x16x32_bf16(afr[m][ks], pf[ks], acc, 0, 0, 0);
                #pragma unroll
                for (int j = 0; j < 4; ++j) {
                    int i = m * 16 + rowg * 4 + j;
                    if (st_l[i] == t)
                        hs[i][ctg * 16 + col_l] = acc[j] + bval;
                }
            }
        }
    }
    __syncthreads();

    {
        int i = tid >> 3;
        int d0 = (tid & 7) * 16;
        int sp = sp0 + i;
        int nid = nid_l[i];
        int t = st_l[i];
        float alpha = 1.f / (1.f + expf(-skip[t]));
        const float* xr = x + (size_t)nid * 128 + d0;
        float hv[16];
        float s1 = 0.f, s2 = 0.f;
        #pragma unroll
        for (int c = 0; c < 4; ++c) {
            float4 xf = *reinterpret_cast<const float4*>(xr + c * 4);
            float4 tf;
            tf.x = hs[i][d0 + c * 4 + 0]; tf.y = hs[i][d0 + c * 4 + 1];
            tf.z = hs[i][d0 + c * 4 + 2]; tf.w = hs[i][d0 + c * 4 + 3];
            hv[c * 4 + 0] = tf.x * alpha + xf.x * (1.f - alpha);
            hv[c * 4 + 1] = tf.y * alpha + xf.y * (1.f - alpha);
            hv[c * 4 + 2] = tf.z * alpha + xf.z * (1.f - alpha);
            hv[c * 4 + 3] = tf.w * alpha + xf.w * (1.f - alpha);
            #pragma unroll
            for (int j = 0; j < 4; ++j) { s1 += hv[c * 4 + j]; s2 += hv[c * 4 + j] * hv[c * 4 + j]; }
        }
        #pragma unroll
        for (int off = 1; off < 8; off <<= 1) {
            s1 += __shfl_xor(s1, off);
            s2 += __shfl_xor(s2, off);
        }
        float mu = s1 * (1.f / 128.f);
        float var = s2 * (1.f / 128.f) - mu * mu;
        float inv = 1.f / sqrtf(var + 1e-5f);
        if (sp < N) {
            float* orow = out + (size_t)nid * 128 + d0;
            const float* gr = gamma + t * 128 + d0;
            const float* br = beta + t * 128 + d0;
            #pragma unroll
            for (int c = 0; c < 4; ++c) {
                float4 gf = *reinterpret_cast<const float4*>(gr + c * 4);
                float4 bf = *reinterpret_cast<const float4*>(br + c * 4);
                float4 of;
                of.x = (hv[c * 4 + 0] - mu) * inv * gf.x + bf.x;
                of.y = (hv[c * 4 + 1] - mu) * inv * gf.y + bf.y;
                of.z = (hv[c * 4 + 2] - mu) * inv * gf.z + bf.z;
                of.w = (hv[c * 4 + 3] - mu) * inv * gf.w + bf.w;
                *reinterpret_cast<float4*>(orow + c * 4) = of;
            }
        }
    }
}

extern "C" void kernel_launch(void* const* d_in, const int* in_sizes, int n_in,
                              void* d_out, int out_size, void* d_ws, size_t ws_size,
                              hipStream_t stream) {
    const float* node_inp = (const float*)d_in[0];
    const int*   node_type = (const int*)d_in[1];
    const int*   edge_index = (const int*)d_in[2];
    const int*   edge_type = (const int*)d_in[3];
    const int*   edge_time = (const int*)d_in[4];
    const float* Wk = (const float*)d_in[5];
    const float* bk = (const float*)d_in[6];
    const float* Wq = (const float*)d_in[7];
    const float* bq = (const float*)d_in[8];
    const float* Wv = (const float*)d_in[9];
    const float* bv = (const float*)d_in[10];
    const float* Wa = (const float*)d_in[11];
    const float* ba = (const float*)d_in[12];
    const float* gamma = (const float*)d_in[13];
    const float* beta = (const float*)d_in[14];
    const float* rel_pri = (const float*)d_in[15];
    const float* rel_att = (const float*)d_in[16];
    const float* rel_msg = (const float*)d_in[17];
    const float* skip = (const float*)d_in[18];
    const float* rte_W = (const float*)d_in[19];
    const float* rte_b = (const float*)d_in[20];

    int N = in_sizes[0] / 128;   // 50000
    int E = in_sizes[3];         // 600000

    char* base = (char*)d_ws;
    unsigned char* knvm8 = (unsigned char*)base;      base += (size_t)N * 4 * 256;
    unsigned char* qa8 = (unsigned char*)base;        base += (size_t)N * 4 * 128;
    unsigned short* aggr_bf = (unsigned short*)base;  base += (size_t)N * 128 * 2;
    unsigned char* rtec8 = (unsigned char*)base;      base += (size_t)NT * NR * MAXLEN * 256;
    short* PW2 = (short*)base;                base += (size_t)10 * NT * 128 * 128 * 2;
    float* PB = (float*)base;                 base += (size_t)10 * NT * 128 * 4;
    int* deg = (int*)base;                    base += (size_t)N * 4;
    int* deg_s = (int*)base;                  base += (size_t)N * 4;
    int* cursor = (int*)base;                 base += (size_t)N * 4;
    int* excl = (int*)base;                   base += (size_t)N * 4;
    int* row_start = (int*)base;              base += (size_t)N * 4;
    int* nlist = (int*)base;                  base += (size_t)N * 4;
    int* spos = (int*)base;                   base += (size_t)N * 4;
    int* stype_s = (int*)base;                base += (size_t)N * 4;
    int* bsum = (int*)base;                   base += 256 * 4;
    int* dcnt = (int*)base;                   base += 256 * 4;
    int* dcur = (int*)base;                   base += 256 * 4;
    int* dbase = (int*)base;                  base += 256 * 4;
    base = (char*)(((size_t)base + 15) & ~(size_t)15);
    unsigned* ebuf = (unsigned*)base;         base += (size_t)E * 4;

    int nb = (N + 255) / 256;
    int ng = (N + 255) / 256;

    zero_kernel<<<256, 256, 0, stream>>>(deg, cursor, dcnt, dcur, N);
    deg_kernel<<<1024, 256, 0, stream>>>(edge_index, deg, E);
    histA<<<ng, 256, 0, stream>>>(node_type, deg, dcnt, N);
    histB<<<1, 256, 0, stream>>>(dcnt, dbase);
    histC<<<ng, 256, 0, stream>>>(node_type, deg, dbase, dcur, nlist, spos, stype_s, deg_s, N);
    scanA<<<nb, 256, 0, stream>>>(deg_s, excl, bsum, N);
    scanB<<<1, 256, 0, stream>>>(bsum, nb);
    scanC<<<nb, 256, 0, stream>>>(excl, bsum, row_start, N);
    scatter_kernel<<<1024, 256, 0, stream>>>(edge_index, edge_type, edge_time, spos, dbase,
                                             row_start, cursor, ebuf, E);
    dim3 gt(MAXLEN, NT);
    rte_tables<<<gt, 128, 0, stream>>>(rte_W, rte_b, Wk, Wv, rel_msg, rtec8);
    pack_w9<<<340, 256, 0, stream>>>(Wk, Wq, Wv, Wa, bk, bq, bv, ba,
                                     rel_att, rel_msg, rel_pri, PW2, PB);
    kqv2<<<(N + 31) / 32, 256, 0, stream>>>(node_inp, nlist, stype_s, PW2, PB,
                                            knvm8, qa8, N);
    fused_edge_attn<<<(N + 3) / 4, 256, 0, stream>>>(ebuf, row_start, deg_s,
                                                     knvm8, rtec8, qa8, aggr_bf, N);
    update_sorted<<<(N + 31) / 32, 256, 0, stream>>>(node_inp, nlist, stype_s, PW2, PB,
                                                     gamma, beta, skip, aggr_bf, (float*)d_out, N);
}

// Round 15
// 226.356 us; speedup vs baseline: 1.0575x; 1.0575x over previous
//
#include <hip/hip_runtime.h>
#include <hip/hip_fp16.h>
#include <math.h>

#define NH 8
#define NT 4
#define NR 4
#define MAXLEN 240

typedef __attribute__((ext_vector_type(8))) short bf16x8;
typedef __attribute__((ext_vector_type(4))) float f32x4;
typedef __attribute__((ext_vector_type(2))) float f32x2;

#if defined(__has_builtin)
#if __has_builtin(__builtin_amdgcn_cvt_pk_f32_fp8) && __has_builtin(__builtin_amdgcn_cvt_pk_fp8_f32)
#define HAS_HW_FP8 1
#endif
#endif

__device__ __forceinline__ unsigned short f2bf(float x) {
    unsigned u = __float_as_uint(x);
    u += 0x7fffu + ((u >> 16) & 1u);
    return (unsigned short)(u >> 16);
}
__device__ __forceinline__ float bflo(unsigned u) { return __uint_as_float(u << 16); }
__device__ __forceinline__ float bfhi(unsigned u) { return __uint_as_float(u & 0xffff0000u); }
__device__ __forceinline__ unsigned pack2(float a, float b) {
    return (unsigned)f2bf(a) | ((unsigned)f2bf(b) << 16);
}

// ---- fp8 e4m3 codec (true scale) ----
__device__ __forceinline__ void fp8x4_dec(unsigned w, float* f) {
#ifdef HAS_HW_FP8
    f32x2 lo = __builtin_amdgcn_cvt_pk_f32_fp8(w, false);
    f32x2 hi = __builtin_amdgcn_cvt_pk_f32_fp8(w, true);
    f[0] = lo[0]; f[1] = lo[1]; f[2] = hi[0]; f[3] = hi[1];
#else
    unsigned ev = w & 0x00ff00ffu;
    unsigned od = (w >> 8) & 0x00ff00ffu;
    unsigned he = (((ev << 8) & 0x80008000u) | ((ev << 7) & 0x3f803f80u)) + 0x04000400u;
    unsigned ho = (((od << 8) & 0x80008000u) | ((od << 7) & 0x3f803f80u)) + 0x04000400u;
    __half2 h2e = *reinterpret_cast<__half2*>(&he);
    __half2 h2o = *reinterpret_cast<__half2*>(&ho);
    float2 fe = __half22float2(h2e);
    float2 fo = __half22float2(h2o);
    f[0] = fe.x; f[1] = fo.x; f[2] = fe.y; f[3] = fo.y;
#endif
}
__device__ __forceinline__ unsigned fp8x2_enc(float a, float b) {
#ifdef HAS_HW_FP8
    return (unsigned)__builtin_amdgcn_cvt_pk_fp8_f32(a, b, 0, false) & 0xffffu;
#else
    auto enc1 = [](float x) -> unsigned {
        float cl = fminf(fmaxf(x, -448.f), 448.f);
        __half h = __float2half(cl * 0.00390625f);
        unsigned short hr = *reinterpret_cast<unsigned short*>(&h);
        unsigned short rnd = (unsigned short)((hr & 0x7fff) + 0x3f + ((hr >> 7) & 1));
        return (unsigned)(((rnd >> 7) & 0x7f) | ((hr >> 8) & 0x80));
    };
    return enc1(a) | (enc1(b) << 8);
#endif
}

__global__ void zero_kernel(int* deg, int* cursor, int* dcnt, int* dcur, int N) {
    int i = blockIdx.x * blockDim.x + threadIdx.x;
    int stride = gridDim.x * blockDim.x;
    if (i < 256) { dcnt[i] = 0; dcur[i] = 0; }
    for (int j = i; j < N; j += stride) { deg[j] = 0; cursor[j] = 0; }
}

__global__ void deg_kernel(const int* __restrict__ ei, int* __restrict__ deg, int E) {
    int i = blockIdx.x * blockDim.x + threadIdx.x;
    int stride = gridDim.x * blockDim.x;
    for (int e = i; e < E; e += stride) atomicAdd(&deg[ei[E + e]], 1);
}

// 256-bucket key: type*64 + (63 - min(deg,63))
__global__ __launch_bounds__(256) void histA(const int* __restrict__ ntype,
                                             const int* __restrict__ deg,
                                             int* __restrict__ dcnt, int N) {
    __shared__ int h[256];
    int tid = threadIdx.x;
    h[tid] = 0;
    __syncthreads();
    int i = blockIdx.x * 256 + tid;
    if (i < N) atomicAdd(&h[ntype[i] * 64 + 63 - min(deg[i], 63)], 1);
    __syncthreads();
    if (h[tid]) atomicAdd(&dcnt[tid], h[tid]);
}

__global__ __launch_bounds__(256) void histB(const int* __restrict__ dcnt,
                                             int* __restrict__ dbase) {
    __shared__ int tmp[256];
    int v = dcnt[threadIdx.x];
    tmp[threadIdx.x] = v;
    __syncthreads();
    #pragma unroll
    for (int off = 1; off < 256; off <<= 1) {
        int t = threadIdx.x >= off ? tmp[threadIdx.x - off] : 0;
        __syncthreads();
        tmp[threadIdx.x] += t;
        __syncthreads();
    }
    dbase[threadIdx.x] = tmp[threadIdx.x] - v;
}

__global__ __launch_bounds__(256) void histC(const int* __restrict__ ntype,
                                             const int* __restrict__ deg,
                                             const int* __restrict__ dbase, int* __restrict__ dcur,
                                             int* __restrict__ nlist, int* __restrict__ spos,
                                             int* __restrict__ stype_s, int* __restrict__ deg_s,
                                             int N) {
    __shared__ int h[256];
    __shared__ int bb[256];
    __shared__ int cur[256];
    int tid = threadIdx.x;
    h[tid] = 0; cur[tid] = 0;
    __syncthreads();
    int i = blockIdx.x * 256 + tid;
    int b = -1, t = 0, dg = 0;
    if (i < N) {
        t = ntype[i]; dg = deg[i];
        b = t * 64 + 63 - min(dg, 63);
        atomicAdd(&h[b], 1);
    }
    __syncthreads();
    if (h[tid]) bb[tid] = atomicAdd(&dcur[tid], h[tid]);
    __syncthreads();
    if (i < N) {
        int r = atomicAdd(&cur[b], 1);
        int p = dbase[b] + bb[b] + r;
        nlist[p] = i;
        spos[i] = p;
        stype_s[p] = t;
        deg_s[p] = dg;
    }
}

__global__ __launch_bounds__(256) void scanA(const int* __restrict__ deg, int* __restrict__ excl,
                                             int* __restrict__ bsum, int N) {
    __shared__ int tmp[256];
    int i = blockIdx.x * 256 + threadIdx.x;
    int v = i < N ? deg[i] : 0;
    tmp[threadIdx.x] = v;
    __syncthreads();
    #pragma unroll
    for (int off = 1; off < 256; off <<= 1) {
        int t = threadIdx.x >= off ? tmp[threadIdx.x - off] : 0;
        __syncthreads();
        tmp[threadIdx.x] += t;
        __syncthreads();
    }
    if (i < N) excl[i] = tmp[threadIdx.x] - v;
    if (threadIdx.x == 255) bsum[blockIdx.x] = tmp[255];
}

__global__ __launch_bounds__(256) void scanB(int* __restrict__ bsum, int nb) {
    __shared__ int tmp[256];
    int v = threadIdx.x < nb ? bsum[threadIdx.x] : 0;
    tmp[threadIdx.x] = v;
    __syncthreads();
    #pragma unroll
    for (int off = 1; off < 256; off <<= 1) {
        int t = threadIdx.x >= off ? tmp[threadIdx.x - off] : 0;
        __syncthreads();
        tmp[threadIdx.x] += t;
        __syncthreads();
    }
    if (threadIdx.x < nb) bsum[threadIdx.x] = tmp[threadIdx.x] - v;
}

__global__ void scanC(const int* __restrict__ excl, const int* __restrict__ bsum,
                      int* __restrict__ row_start, int N) {
    int i = blockIdx.x * blockDim.x + threadIdx.x;
    if (i < N) row_start[i] = excl[i] + bsum[i >> 8];
}

// ebuf entry: sps(17) | r(2)@17 | tm(8)@19 | st(2)@27
__global__ void scatter_kernel(const int* __restrict__ ei, const int* __restrict__ etype,
                               const int* __restrict__ etime, const int* __restrict__ spos,
                               const int* __restrict__ dbase,
                               const int* __restrict__ row_start, int* __restrict__ cursor,
                               unsigned* __restrict__ ebuf, int E) {
    int tb1 = dbase[64], tb2 = dbase[128], tb3 = dbase[192];
    int i = blockIdx.x * blockDim.x + threadIdx.x;
    int stride = gridDim.x * blockDim.x;
    for (int e = i; e < E; e += stride) {
        int sps = spos[ei[e]];
        int spt = spos[ei[E + e]];
        int st = (sps >= tb1) + (sps >= tb2) + (sps >= tb3);
        int pos = atomicAdd(&cursor[spt], 1);
        ebuf[row_start[spt] + pos] =
            (unsigned)sps | ((unsigned)etype[e] << 17) | ((unsigned)etime[e] << 19) | ((unsigned)st << 27);
    }
}

// Fused RTE tables -> combined fp8 table rtec8[(st*4+r)*240+tm][256B]
__global__ __launch_bounds__(128) void rte_tables(
    const float* __restrict__ rte_W, const float* __restrict__ rte_b,
    const float* __restrict__ Wk, const float* __restrict__ Wv,
    const float* __restrict__ rel_msg,
    unsigned char* __restrict__ rtec8) {
    int m = blockIdx.x, t = blockIdx.y, d = threadIdx.x;
    __shared__ float emb[128];
    __shared__ float sr[128];
    __shared__ float vr[128];
    int j2 = d & ~1;
    float div = expf((float)j2 * (-9.210340371976184f / 128.f));
    float ang = (float)m * div;
    emb[d] = ((d & 1) ? cosf(ang) : sinf(ang)) * 0.08838834764831845f;
    __syncthreads();
    float ro = rte_b[d];
    #pragma unroll 8
    for (int i = 0; i < 128; ++i) ro += emb[i] * rte_W[i * 128 + d];
    sr[d] = ro;
    __syncthreads();
    float ak = 0.f, av = 0.f;
    for (int i = 0; i < 128; ++i) {
        float rv = sr[i];
        ak += rv * Wk[(t * 128 + i) * 128 + d];
        av += rv * Wv[(t * 128 + i) * 128 + d];
    }
    unsigned char kb = (unsigned char)(fp8x2_enc(fminf(fmaxf(ak, -440.f), 440.f), 0.f) & 0xff);
    int koff = (d >> 3) * 16 + 8 + (d & 7);
    #pragma unroll
    for (int r = 0; r < NR; ++r)
        rtec8[(size_t)((t * 4 + r) * MAXLEN + m) * 256 + koff] = kb;
    vr[d] = av;
    __syncthreads();
    int h = d >> 4, dd = d & 15;
    int voff = (d >> 3) * 16 + (d & 7);
    for (int r = 0; r < NR; ++r) {
        float acc = 0.f;
        #pragma unroll
        for (int k = 0; k < 16; ++k)
            acc += vr[h * 16 + k] * rel_msg[((r * NH + h) * 16 + k) * 16 + dd];
        unsigned char vb = (unsigned char)(fp8x2_enc(fminf(fmaxf(acc, -440.f), 440.f), 0.f) & 0xff);
        rtec8[(size_t)((t * 4 + r) * MAXLEN + m) * 256 + voff] = vb;
    }
}

// Fold rel transforms into weights (true scale).
__global__ __launch_bounds__(256) void pack_w9(
    const float* __restrict__ Wk, const float* __restrict__ Wq,
    const float* __restrict__ Wv, const float* __restrict__ Wa,
    const float* __restrict__ bk, const float* __restrict__ bq,
    const float* __restrict__ bv, const float* __restrict__ ba,
    const float* __restrict__ rel_att, const float* __restrict__ rel_msg,
    const float* __restrict__ rel_pri,
    short* __restrict__ PW2, float* __restrict__ PB) {
    if (blockIdx.x >= 320) {
        int bidx = (blockIdx.x - 320) * 256 + threadIdx.x;
        int col = bidx & 127, t = (bidx >> 7) & 3, set = bidx >> 9;
        int h = col >> 4, kk = col & 15;
        float val;
        if (set == 0) val = bk[t * 128 + col];
        else if (set == 9) val = ba[t * 128 + col];
        else if (set <= 4) {
            int r = set - 1;
            float pri = rel_pri[r * NH + h] * 0.25f;
            float acc = 0.f;
            #pragma unroll
            for (int dp = 0; dp < 16; ++dp)
                acc += bq[t * 128 + h * 16 + dp] * rel_att[((r * NH + h) * 16 + kk) * 16 + dp];
            val = acc * pri;
        } else {
            int r = set - 5;
            float acc = 0.f;
            #pragma unroll
            for (int kp = 0; kp < 16; ++kp)
                acc += bv[t * 128 + h * 16 + kp] * rel_msg[((r * NH + h) * 16 + kp) * 16 + kk];
            val = acc;
        }
        PB[bidx] = val;
        return;
    }
    int idx = blockIdx.x * 256 + threadIdx.x;
    int lane = idx & 63;
    int ks = (idx >> 6) & 3;
    int ctg = (idx >> 8) & 7;
    int t = (idx >> 11) & 3;
    int set = idx >> 13;
    int col = ctg * 16 + (lane & 15);
    int k0 = ks * 32 + (lane >> 4) * 8;
    int h = col >> 4, kk = col & 15;
    unsigned short o[8];
    if (set == 0 || set == 9) {
        const float* W = (set == 0 ? Wk : Wa) + t * 16384;
        #pragma unroll
        for (int j = 0; j < 8; ++j) o[j] = f2bf(W[(k0 + j) * 128 + col]);
    } else if (set <= 4) {
        int r = set - 1;
        float pri = rel_pri[r * NH + h] * 0.25f;
        float Ar[16];
        #pragma unroll
        for (int dp = 0; dp < 16; ++dp)
            Ar[dp] = rel_att[((r * NH + h) * 16 + kk) * 16 + dp] * pri;
        #pragma unroll
        for (int j = 0; j < 8; ++j) {
            const float* wr = Wq + (size_t)(t * 128 + k0 + j) * 128 + h * 16;
            float acc = 0.f;
            #pragma unroll
            for (int dp = 0; dp < 16; ++dp) acc += wr[dp] * Ar[dp];
            o[j] = f2bf(acc);
        }
    } else {
        int r = set - 5;
        float Mc[16];
        #pragma unroll
        for (int kp = 0; kp < 16; ++kp)
            Mc[kp] = rel_msg[((r * NH + h) * 16 + kp) * 16 + kk];
        #pragma unroll
        for (int j = 0; j < 8; ++j) {
            const float* wr = Wv + (size_t)(t * 128 + k0 + j) * 128 + h * 16;
            float acc = 0.f;
            #pragma unroll
            for (int kp = 0; kp < 16; ++kp) acc += wr[kp] * Mc[kp];
            o[j] = f2bf(acc);
        }
    }
    uint4 pk;
    pk.x = (unsigned)o[0] | ((unsigned)o[1] << 16);
    pk.y = (unsigned)o[2] | ((unsigned)o[3] << 16);
    pk.z = (unsigned)o[4] | ((unsigned)o[5] << 16);
    pk.w = (unsigned)o[6] | ((unsigned)o[7] << 16);
    *reinterpret_cast<uint4*>(PW2 + (size_t)idx * 8) = pk;
}

#define S8 144
#define KST 144

// 32 sorted nodes/tile: MFMA GEMM, ALL 9 output sets fp8, double-buffered staging.
__global__ __launch_bounds__(256, 4) void kqv2(
    const float* __restrict__ x, const int* __restrict__ nlist_,
    const int* __restrict__ stype_s, const short* __restrict__ PW2,
    const float* __restrict__ PB,
    unsigned char* __restrict__ knvm8, unsigned char* __restrict__ qa8, int N) {
    __shared__ short af_l[2][4][64][8];
    __shared__ unsigned char obuf[2][32 * S8];
    __shared__ unsigned char kn_keep[32 * KST];
    __shared__ int st_l[32];
    const int tid = threadIdx.x;
    const int sp0 = blockIdx.x * 32;
    if (tid < 32) {
        int sp = sp0 + tid;
        st_l[tid] = stype_s[sp < N ? sp : N - 1];
    }
    {
        int i = tid >> 3;
        int d0 = (tid & 7) * 16;
        int sp = sp0 + i;
        int nid = nlist_[sp < N ? sp : N - 1];
        const float* xr = x + (size_t)nid * 128 + d0;
        float4 f0 = *reinterpret_cast<const float4*>(xr);
        float4 f1 = *reinterpret_cast<const float4*>(xr + 4);
        float4 f2 = *reinterpret_cast<const float4*>(xr + 8);
        float4 f3 = *reinterpret_cast<const float4*>(xr + 12);
        int m = i >> 4, rr = i & 15;
        int ks = d0 >> 5;
        int sub = (d0 >> 3) & 3;
        uint4 p0, p1;
        p0.x = pack2(f0.x, f0.y); p0.y = pack2(f0.z, f0.w);
        p0.z = pack2(f1.x, f1.y); p0.w = pack2(f1.z, f1.w);
        p1.x = pack2(f2.x, f2.y); p1.y = pack2(f2.z, f2.w);
        p1.z = pack2(f3.x, f3.y); p1.w = pack2(f3.z, f3.w);
        *reinterpret_cast<uint4*>(&af_l[m][ks][sub * 16 + rr][0]) = p0;
        *reinterpret_cast<uint4*>(&af_l[m][ks][(sub + 1) * 16 + rr][0]) = p1;
    }
    __syncthreads();

    const int lane = tid & 63, w = tid >> 6;
    const int col_l = lane & 15, rowg = lane >> 4;
    const int t0 = st_l[0], t1 = st_l[31];

    bf16x8 afr[2][4];
    #pragma unroll
    for (int m = 0; m < 2; ++m)
        #pragma unroll
        for (int ks = 0; ks < 4; ++ks)
            afr[m][ks] = *reinterpret_cast<const bf16x8*>(&af_l[m][ks][lane][0]);

    const int wi = tid >> 3, wseg = tid & 7;
    const int wsp = sp0 + wi;

    for (int set = 0; set < 9; ++set) {
        unsigned char* buf = &obuf[set & 1][0];
        for (int t = t0; t <= t1; ++t) {
            #pragma unroll
            for (int c = 0; c < 2; ++c) {
                int ctg = w + c * 4;
                bf16x8 pf[4];
                #pragma unroll
                for (int ks = 0; ks < 4; ++ks)
                    pf[ks] = *reinterpret_cast<const bf16x8*>(
                        PW2 + ((size_t)((((set * 4 + t) * 8 + ctg) * 4 + ks) * 64 + lane)) * 8);
                float bval = PB[(set * 4 + t) * 128 + ctg * 16 + col_l];
                #pragma unroll
                for (int m = 0; m < 2; ++m) {
                    f32x4 acc = {0.f, 0.f, 0.f, 0.f};
                    #pragma unroll
                    for (int ks = 0; ks < 4; ++ks)
                        acc = __builtin_amdgcn_mfma_f32_16x16x32_bf16(afr[m][ks], pf[ks], acc, 0, 0, 0);
                    float c0 = fminf(fmaxf(acc[0] + bval, -440.f), 440.f);
                    float c1 = fminf(fmaxf(acc[1] + bval, -440.f), 440.f);
                    float c2 = fminf(fmaxf(acc[2] + bval, -440.f), 440.f);
                    float c3 = fminf(fmaxf(acc[3] + bval, -440.f), 440.f);
                    unsigned pA = fp8x2_enc(c0, c1);
                    unsigned pB = fp8x2_enc(c2, c3);
                    unsigned char by[4];
                    by[0] = (unsigned char)(pA & 0xff);
                    by[1] = (unsigned char)((pA >> 8) & 0xff);
                    by[2] = (unsigned char)(pB & 0xff);
                    by[3] = (unsigned char)((pB >> 8) & 0xff);
                    #pragma unroll
                    for (int j = 0; j < 4; ++j) {
                        int i = m * 16 + rowg * 4 + j;
                        if (st_l[i] == t)
                            buf[i * S8 + ctg * 16 + col_l] = by[j];
                    }
                }
            }
        }
        __syncthreads();
        if (set == 0) {
            *reinterpret_cast<uint4*>(&kn_keep[wi * KST + wseg * 16]) =
                *reinterpret_cast<const uint4*>(&buf[wi * S8 + wseg * 16]);
        } else if (set <= 4) {
            if (wsp < N) {
                int r = set - 1;
                *reinterpret_cast<uint4*>(qa8 + (size_t)(wsp * 4 + r) * 128 + wseg * 16) =
                    *reinterpret_cast<const uint4*>(&buf[wi * S8 + wseg * 16]);
            }
        } else {
            if (wsp < N) {
                int r = set - 5;
                unsigned char* dst = knvm8 + (size_t)(wsp * 4 + r) * 256;
                #pragma unroll
                for (int cc = 0; cc < 2; ++cc) {
                    int c = wseg * 2 + cc;
                    uint2 vmc = *reinterpret_cast<const uint2*>(&buf[wi * S8 + c * 8]);
                    uint2 knc = *reinterpret_cast<const uint2*>(&kn_keep[wi * KST + c * 8]);
                    uint4 outv;
                    outv.x = vmc.x; outv.y = vmc.y; outv.z = knc.x; outv.w = knc.y;
                    *reinterpret_cast<uint4*>(dst + c * 16) = outv;
                }
            }
        }
    }
}

// One sorted node per 16 lanes (4 nodes/wave); 4-edge unroll = 8 gathers in
// flight per group (32 per wave). qa fp8 decoded once per node.
__global__ __launch_bounds__(256) void fused_edge_attn(
    const unsigned* __restrict__ ebuf, const int* __restrict__ row_start,
    const int* __restrict__ deg_s,
    const unsigned char* __restrict__ knvm8, const unsigned char* __restrict__ rtec8,
    const unsigned char* __restrict__ qa8,
    unsigned short* __restrict__ aggr_bf, int N) {
    int sp = blockIdx.x * 16 + (threadIdx.x >> 4);
    int l16 = threadIdx.x & 15;
    if (sp >= N) return;
    uint4 q[4];
    #pragma unroll
    for (int r = 0; r < 4; ++r) {
        uint2 qv = *reinterpret_cast<const uint2*>(qa8 + (size_t)(sp * 4 + r) * 128 + l16 * 8);
        float f[8];
        fp8x4_dec(qv.x, f); fp8x4_dec(qv.y, f + 4);
        q[r].x = pack2(f[0], f[1]); q[r].y = pack2(f[2], f[3]);
        q[r].z = pack2(f[4], f[5]); q[r].w = pack2(f[6], f[7]);
    }
    int start = row_start[sp], cnt = deg_s[sp];
    float den = 0.f;
    float acc[8] = {0.f, 0.f, 0.f, 0.f, 0.f, 0.f, 0.f, 0.f};
    int i = 0;
    for (; i + 4 <= cnt; i += 4) {
        unsigned em[4];
        #pragma unroll
        for (int u = 0; u < 4; ++u) em[u] = ebuf[start + i + u];
        uint4 ga[4], gb[4];
        #pragma unroll
        for (int u = 0; u < 4; ++u) {
            int sps = em[u] & 0x1ffff, r = (em[u] >> 17) & 3;
            int tm = (em[u] >> 19) & 255, st = (em[u] >> 27) & 3;
            ga[u] = *reinterpret_cast<const uint4*>(knvm8 + (size_t)(sps * 4 + r) * 256 + l16 * 16);
            gb[u] = *reinterpret_cast<const uint4*>(rtec8 + (size_t)((st * 4 + r) * MAXLEN + tm) * 256 + l16 * 16);
        }
        #pragma unroll
        for (int u = 0; u < 4; ++u) {
            int r = (em[u] >> 17) & 3;
            float mf[8], kf[8], mr[8], kr[8];
            fp8x4_dec(ga[u].x, mf); fp8x4_dec(ga[u].y, mf + 4);
            fp8x4_dec(ga[u].z, kf); fp8x4_dec(ga[u].w, kf + 4);
            fp8x4_dec(gb[u].x, mr); fp8x4_dec(gb[u].y, mr + 4);
            fp8x4_dec(gb[u].z, kr); fp8x4_dec(gb[u].w, kr + 4);
            uint4 q0 = q[r];
            float p = (kf[0] + kr[0]) * bflo(q0.x) + (kf[1] + kr[1]) * bfhi(q0.x)
                    + (kf[2] + kr[2]) * bflo(q0.y) + (kf[3] + kr[3]) * bfhi(q0.y)
                    + (kf[4] + kr[4]) * bflo(q0.z) + (kf[5] + kr[5]) * bfhi(q0.z)
                    + (kf[6] + kr[6]) * bflo(q0.w) + (kf[7] + kr[7]) * bfhi(q0.w);
            p += __shfl_xor(p, 1);
            float w0 = __expf(p);
            den += w0;
            #pragma unroll
            for (int j = 0; j < 8; ++j)
                acc[j] += w0 * (mf[j] + mr[j]);
        }
    }
    for (; i < cnt; ++i) {
        unsigned e0 = ebuf[start + i];
        int sps0 = e0 & 0x1ffff, r0 = (e0 >> 17) & 3, tm0 = (e0 >> 19) & 255, st0 = (e0 >> 27) & 3;
        uint4 g1 = *reinterpret_cast<const uint4*>(knvm8 + (size_t)(sps0 * 4 + r0) * 256 + l16 * 16);
        uint4 g2 = *reinterpret_cast<const uint4*>(rtec8 + (size_t)((st0 * 4 + r0) * MAXLEN + tm0) * 256 + l16 * 16);
        float mf[8], kf[8], mr[8], kr[8];
        fp8x4_dec(g1.x, mf); fp8x4_dec(g1.y, mf + 4);
        fp8x4_dec(g1.z, kf); fp8x4_dec(g1.w, kf + 4);
        fp8x4_dec(g2.x, mr); fp8x4_dec(g2.y, mr + 4);
        fp8x4_dec(g2.z, kr); fp8x4_dec(g2.w, kr + 4);
        uint4 q0 = q[r0];
        float p = (kf[0] + kr[0]) * bflo(q0.x) + (kf[1] + kr[1]) * bfhi(q0.x)
                + (kf[2] + kr[2]) * bflo(q0.y) + (kf[3] + kr[3]) * bfhi(q0.y)
                + (kf[4] + kr[4]) * bflo(q0.z) + (kf[5] + kr[5]) * bfhi(q0.z)
                + (kf[6] + kr[6]) * bflo(q0.w) + (kf[7] + kr[7]) * bfhi(q0.w);
        p += __shfl_xor(p, 1);
        float w0 = __expf(p);
        den += w0;
        #pragma unroll
        for (int j = 0; j < 8; ++j)
            acc[j] += w0 * (mf[j] + mr[j]);
    }
    float inv = den > 0.f ? 1.f / den : 0.f;
    uint4 o;
    o.x = pack2(acc[0] * inv, acc[1] * inv);
    o.y = pack2(acc[2] * inv, acc[3] * inv);
    o.z = pack2(acc[4] * inv, acc[5] * inv);
    o.w = pack2(acc[6] * inv, acc[7] * inv);
    *reinterpret_cast<uint4*>(aggr_bf + (size_t)sp * 128 + l16 * 8) = o;
}

// 32 sorted nodes/tile: gelu(aggr bf16) -> MFMA Wa -> skip-blend -> LN -> scatter out
__global__ __launch_bounds__(256, 4) void update_sorted(
    const float* __restrict__ x, const int* __restrict__ nlist_,
    const int* __restrict__ stype_s, const short* __restrict__ PW2,
    const float* __restrict__ PB, const float* __restrict__ gamma,
    const float* __restrict__ beta, const float* __restrict__ skip,
    const unsigned short* __restrict__ aggr_bf, float* __restrict__ out, int N) {
    __shared__ short af_l[2][4][64][8];
    __shared__ float hs[32][128];
    __shared__ int st_l[32];
    __shared__ int nid_l[32];
    const int tid = threadIdx.x;
    const int sp0 = blockIdx.x * 32;
    if (tid < 32) {
        int sp = sp0 + tid;
        int spc = sp < N ? sp : N - 1;
        st_l[tid] = stype_s[spc];
        nid_l[tid] = nlist_[spc];
    }
    {
        int i = tid >> 3;
        int d0 = (tid & 7) * 16;
        int spc = sp0 + i < N ? sp0 + i : N - 1;
        const unsigned short* ar = aggr_bf + (size_t)spc * 128 + d0;
        uint4 v0 = *reinterpret_cast<const uint4*>(ar);
        uint4 v1 = *reinterpret_cast<const uint4*>(ar + 8);
        unsigned vv[8] = {v0.x, v0.y, v0.z, v0.w, v1.x, v1.y, v1.z, v1.w};
        float g[16];
        #pragma unroll
        for (int c = 0; c < 8; ++c) {
            float a0 = bflo(vv[c]), a1 = bfhi(vv[c]);
            g[c * 2 + 0] = 0.5f * a0 * (1.f + erff(a0 * 0.7071067811865476f));
            g[c * 2 + 1] = 0.5f * a1 * (1.f + erff(a1 * 0.7071067811865476f));
        }
        int m = i >> 4, rr = i & 15;
        int ks = d0 >> 5;
        int sub = (d0 >> 3) & 3;
        uint4 p0, p1;
        p0.x = pack2(g[0], g[1]);  p0.y = pack2(g[2], g[3]);
        p0.z = pack2(g[4], g[5]);  p0.w = pack2(g[6], g[7]);
        p1.x = pack2(g[8], g[9]);  p1.y = pack2(g[10], g[11]);
        p1.z = pack2(g[12], g[13]); p1.w = pack2(g[14], g[15]);
        *reinterpret_cast<uint4*>(&af_l[m][ks][sub * 16 + rr][0]) = p0;
        *reinterpret_cast<uint4*>(&af_l[m][ks][(sub + 1) * 16 + rr][0]) = p1;
    }
    __syncthreads();

    const int lane = tid & 63, w = tid >> 6;
    const int col_l = lane & 15, rowg = lane >> 4;
    const int t0 = st_l[0], t1 = st_l[31];

    bf16x8 afr[2][4];
    #pragma unroll
    for (int m = 0; m < 2; ++m)
        #pragma unroll
        for (int ks = 0; ks < 4; ++ks)
            afr[m][ks] = *reinterpret_cast<const bf16x8*>(&af_l[m][ks][lane][0]);

    for (int t = t0; t <= t1; ++t) {
        #pragma unroll
        for (int c = 0; c < 2; ++c) {
            int ctg = w + c * 4;
            bf16x8 pf[4];
            #pragma unroll
            for (int ks = 0; ks < 4; ++ks)
                pf[ks] = *reinterpret_cast<const bf16x8*>(
                    PW2 + ((size_t)((((9 * 4 + t) * 8 + ctg) * 4 + ks) * 64 + lane)) * 8);
            float bval = PB[(9 * 4 + t) * 128 + ctg * 16 + col_l];
            #pragma unroll
            for (int m = 0; m < 2; ++m) {
                f32x4 acc = {0.f, 0.f, 0.f, 0.f};
                #pragma unroll
                for (int ks = 0; ks < 4; ++ks)
                    acc = __builtin_amdgcn_mfma_f32_16x16x32_bf16(afr[m][ks], pf[ks], acc, 0, 0, 0);
                #pragma unroll
                for (int j = 0; j < 4; ++j) {
                    int i = m * 16 + rowg * 4 + j;
                    if (st_l[i] == t)
                        hs[i][ctg * 16 + col_l] = acc[j] + bval;
                }
            }
        }
    }
    __syncthreads();

    {
        int i = tid >> 3;
        int d0 = (tid & 7) * 16;
        int sp = sp0 + i;
        int nid = nid_l[i];
        int t = st_l[i];
        float alpha = 1.f / (1.f + expf(-skip[t]));
        const float* xr = x + (size_t)nid * 128 + d0;
        float hv[16];
        float s1 = 0.f, s2 = 0.f;
        #pragma unroll
        for (int c = 0; c < 4; ++c) {
            float4 xf = *reinterpret_cast<const float4*>(xr + c * 4);
            float4 tf;
            tf.x = hs[i][d0 + c * 4 + 0]; tf.y = hs[i][d0 + c * 4 + 1];
            tf.z = hs[i][d0 + c * 4 + 2]; tf.w = hs[i][d0 + c * 4 + 3];
            hv[c * 4 + 0] = tf.x * alpha + xf.x * (1.f - alpha);
            hv[c * 4 + 1] = tf.y * alpha + xf.y * (1.f - alpha);
            hv[c * 4 + 2] = tf.z * alpha + xf.z * (1.f - alpha);
            hv[c * 4 + 3] = tf.w * alpha + xf.w * (1.f - alpha);
            #pragma unroll
            for (int j = 0; j < 4; ++j) { s1 += hv[c * 4 + j]; s2 += hv[c * 4 + j] * hv[c * 4 + j]; }
        }
        #pragma unroll
        for (int off = 1; off < 8; off <<= 1) {
            s1 += __shfl_xor(s1, off);
            s2 += __shfl_xor(s2, off);
        }
        float mu = s1 * (1.f / 128.f);
        float var = s2 * (1.f / 128.f) - mu * mu;
        float inv = 1.f / sqrtf(var + 1e-5f);
        if (sp < N) {
            float* orow = out + (size_t)nid * 128 + d0;
            const float* gr = gamma + t * 128 + d0;
            const float* br = beta + t * 128 + d0;
            #pragma unroll
            for (int c = 0; c < 4; ++c) {
                float4 gf = *reinterpret_cast<const float4*>(gr + c * 4);
                float4 bf = *reinterpret_cast<const float4*>(br + c * 4);
                float4 of;
                of.x = (hv[c * 4 + 0] - mu) * inv * gf.x + bf.x;
                of.y = (hv[c * 4 + 1] - mu) * inv * gf.y + bf.y;
                of.z = (hv[c * 4 + 2] - mu) * inv * gf.z + bf.z;
                of.w = (hv[c * 4 + 3] - mu) * inv * gf.w + bf.w;
                *reinterpret_cast<float4*>(orow + c * 4) = of;
            }
        }
    }
}

extern "C" void kernel_launch(void* const* d_in, const int* in_sizes, int n_in,
                              void* d_out, int out_size, void* d_ws, size_t ws_size,
                              hipStream_t stream) {
    const float* node_inp = (const float*)d_in[0];
    const int*   node_type = (const int*)d_in[1];
    const int*   edge_index = (const int*)d_in[2];
    const int*   edge_type = (const int*)d_in[3];
    const int*   edge_time = (const int*)d_in[4];
    const float* Wk = (const float*)d_in[5];
    const float* bk = (const float*)d_in[6];
    const float* Wq = (const float*)d_in[7];
    const float* bq = (const float*)d_in[8];
    const float* Wv = (const float*)d_in[9];
    const float* bv = (const float*)d_in[10];
    const float* Wa = (const float*)d_in[11];
    const float* ba = (const float*)d_in[12];
    const float* gamma = (const float*)d_in[13];
    const float* beta = (const float*)d_in[14];
    const float* rel_pri = (const float*)d_in[15];
    const float* rel_att = (const float*)d_in[16];
    const float* rel_msg = (const float*)d_in[17];
    const float* skip = (const float*)d_in[18];
    const float* rte_W = (const float*)d_in[19];
    const float* rte_b = (const float*)d_in[20];

    int N = in_sizes[0] / 128;   // 50000
    int E = in_sizes[3];         // 600000

    char* base = (char*)d_ws;
    unsigned char* knvm8 = (unsigned char*)base;      base += (size_t)N * 4 * 256;
    unsigned char* qa8 = (unsigned char*)base;        base += (size_t)N * 4 * 128;
    unsigned short* aggr_bf = (unsigned short*)base;  base += (size_t)N * 128 * 2;
    unsigned char* rtec8 = (unsigned char*)base;      base += (size_t)NT * NR * MAXLEN * 256;
    short* PW2 = (short*)base;                base += (size_t)10 * NT * 128 * 128 * 2;
    float* PB = (float*)base;                 base += (size_t)10 * NT * 128 * 4;
    int* deg = (int*)base;                    base += (size_t)N * 4;
    int* deg_s = (int*)base;                  base += (size_t)N * 4;
    int* cursor = (int*)base;                 base += (size_t)N * 4;
    int* excl = (int*)base;                   base += (size_t)N * 4;
    int* row_start = (int*)base;              base += (size_t)N * 4;
    int* nlist = (int*)base;                  base += (size_t)N * 4;
    int* spos = (int*)base;                   base += (size_t)N * 4;
    int* stype_s = (int*)base;                base += (size_t)N * 4;
    int* bsum = (int*)base;                   base += 256 * 4;
    int* dcnt = (int*)base;                   base += 256 * 4;
    int* dcur = (int*)base;                   base += 256 * 4;
    int* dbase = (int*)base;                  base += 256 * 4;
    base = (char*)(((size_t)base + 15) & ~(size_t)15);
    unsigned* ebuf = (unsigned*)base;         base += (size_t)E * 4;

    int nb = (N + 255) / 256;
    int ng = (N + 255) / 256;

    zero_kernel<<<256, 256, 0, stream>>>(deg, cursor, dcnt, dcur, N);
    deg_kernel<<<1024, 256, 0, stream>>>(edge_index, deg, E);
    histA<<<ng, 256, 0, stream>>>(node_type, deg, dcnt, N);
    histB<<<1, 256, 0, stream>>>(dcnt, dbase);
    histC<<<ng, 256, 0, stream>>>(node_type, deg, dbase, dcur, nlist, spos, stype_s, deg_s, N);
    scanA<<<nb, 256, 0, stream>>>(deg_s, excl, bsum, N);
    scanB<<<1, 256, 0, stream>>>(bsum, nb);
    scanC<<<nb, 256, 0, stream>>>(excl, bsum, row_start, N);
    scatter_kernel<<<1024, 256, 0, stream>>>(edge_index, edge_type, edge_time, spos, dbase,
                                             row_start, cursor, ebuf, E);
    dim3 gt(MAXLEN, NT);
    rte_tables<<<gt, 128, 0, stream>>>(rte_W, rte_b, Wk, Wv, rel_msg, rtec8);
    pack_w9<<<340, 256, 0, stream>>>(Wk, Wq, Wv, Wa, bk, bq, bv, ba,
                                     rel_att, rel_msg, rel_pri, PW2, PB);
    kqv2<<<(N + 31) / 32, 256, 0, stream>>>(node_inp, nlist, stype_s, PW2, PB,
                                            knvm8, qa8, N);
    fused_edge_attn<<<(N + 15) / 16, 256, 0, stream>>>(ebuf, row_start, deg_s,
                                                       knvm8, rtec8, qa8, aggr_bf, N);
    update_sorted<<<(N + 31) / 32, 256, 0, stream>>>(node_inp, nlist, stype_s, PW2, PB,
                                                     gamma, beta, skip, aggr_bf, (float*)d_out, N);
}

// Round 16
// 213.462 us; speedup vs baseline: 1.1214x; 1.0604x over previous
//
#include <hip/hip_runtime.h>
#include <hip/hip_fp16.h>
#include <math.h>

#define NH 8
#define NT 4
#define NR 4
#define MAXLEN 240

typedef __attribute__((ext_vector_type(8))) short bf16x8;
typedef __attribute__((ext_vector_type(4))) float f32x4;
typedef __attribute__((ext_vector_type(2))) float f32x2;

#if defined(__has_builtin)
#if __has_builtin(__builtin_amdgcn_cvt_pk_f32_fp8) && __has_builtin(__builtin_amdgcn_cvt_pk_fp8_f32)
#define HAS_HW_FP8 1
#endif
#endif

__device__ __forceinline__ unsigned short f2bf(float x) {
    unsigned u = __float_as_uint(x);
    u += 0x7fffu + ((u >> 16) & 1u);
    return (unsigned short)(u >> 16);
}
__device__ __forceinline__ float bflo(unsigned u) { return __uint_as_float(u << 16); }
__device__ __forceinline__ float bfhi(unsigned u) { return __uint_as_float(u & 0xffff0000u); }
__device__ __forceinline__ unsigned pack2(float a, float b) {
    return (unsigned)f2bf(a) | ((unsigned)f2bf(b) << 16);
}

// ---- fp8 e4m3 codec (true scale) ----
__device__ __forceinline__ void fp8x4_dec(unsigned w, float* f) {
#ifdef HAS_HW_FP8
    f32x2 lo = __builtin_amdgcn_cvt_pk_f32_fp8(w, false);
    f32x2 hi = __builtin_amdgcn_cvt_pk_f32_fp8(w, true);
    f[0] = lo[0]; f[1] = lo[1]; f[2] = hi[0]; f[3] = hi[1];
#else
    unsigned ev = w & 0x00ff00ffu;
    unsigned od = (w >> 8) & 0x00ff00ffu;
    unsigned he = (((ev << 8) & 0x80008000u) | ((ev << 7) & 0x3f803f80u)) + 0x04000400u;
    unsigned ho = (((od << 8) & 0x80008000u) | ((od << 7) & 0x3f803f80u)) + 0x04000400u;
    __half2 h2e = *reinterpret_cast<__half2*>(&he);
    __half2 h2o = *reinterpret_cast<__half2*>(&ho);
    float2 fe = __half22float2(h2e);
    float2 fo = __half22float2(h2o);
    f[0] = fe.x; f[1] = fo.x; f[2] = fe.y; f[3] = fo.y;
#endif
}
__device__ __forceinline__ unsigned fp8x2_enc(float a, float b) {
#ifdef HAS_HW_FP8
    return (unsigned)__builtin_amdgcn_cvt_pk_fp8_f32(a, b, 0, false) & 0xffffu;
#else
    auto enc1 = [](float x) -> unsigned {
        float cl = fminf(fmaxf(x, -448.f), 448.f);
        __half h = __float2half(cl * 0.00390625f);
        unsigned short hr = *reinterpret_cast<unsigned short*>(&h);
        unsigned short rnd = (unsigned short)((hr & 0x7fff) + 0x3f + ((hr >> 7) & 1));
        return (unsigned)(((rnd >> 7) & 0x7f) | ((hr >> 8) & 0x80));
    };
    return enc1(a) | (enc1(b) << 8);
#endif
}

__global__ void deg_kernel(const int* __restrict__ ei, int* __restrict__ deg, int E) {
    int i = blockIdx.x * blockDim.x + threadIdx.x;
    int stride = gridDim.x * blockDim.x;
    for (int e = i; e < E; e += stride) atomicAdd(&deg[ei[E + e]], 1);
}

// 256-bucket key: type*64 + (63 - min(deg,63))
__global__ __launch_bounds__(256) void histA(const int* __restrict__ ntype,
                                             const int* __restrict__ deg,
                                             int* __restrict__ dcnt, int N) {
    __shared__ int h[256];
    int tid = threadIdx.x;
    h[tid] = 0;
    __syncthreads();
    int i = blockIdx.x * 256 + tid;
    if (i < N) atomicAdd(&h[ntype[i] * 64 + 63 - min(deg[i], 63)], 1);
    __syncthreads();
    if (h[tid]) atomicAdd(&dcnt[tid], h[tid]);
}

__global__ __launch_bounds__(256) void histB(const int* __restrict__ dcnt,
                                             int* __restrict__ dbase) {
    __shared__ int tmp[256];
    int v = dcnt[threadIdx.x];
    tmp[threadIdx.x] = v;
    __syncthreads();
    #pragma unroll
    for (int off = 1; off < 256; off <<= 1) {
        int t = threadIdx.x >= off ? tmp[threadIdx.x - off] : 0;
        __syncthreads();
        tmp[threadIdx.x] += t;
        __syncthreads();
    }
    dbase[threadIdx.x] = tmp[threadIdx.x] - v;
}

__global__ __launch_bounds__(256) void histC(const int* __restrict__ ntype,
                                             const int* __restrict__ deg,
                                             const int* __restrict__ dbase, int* __restrict__ dcur,
                                             int* __restrict__ nlist, int* __restrict__ spos,
                                             int* __restrict__ stype_s, int* __restrict__ deg_s,
                                             int N) {
    __shared__ int h[256];
    __shared__ int bb[256];
    __shared__ int cur[256];
    int tid = threadIdx.x;
    h[tid] = 0; cur[tid] = 0;
    __syncthreads();
    int i = blockIdx.x * 256 + tid;
    int b = -1, t = 0, dg = 0;
    if (i < N) {
        t = ntype[i]; dg = deg[i];
        b = t * 64 + 63 - min(dg, 63);
        atomicAdd(&h[b], 1);
    }
    __syncthreads();
    if (h[tid]) bb[tid] = atomicAdd(&dcur[tid], h[tid]);
    __syncthreads();
    if (i < N) {
        int r = atomicAdd(&cur[b], 1);
        int p = dbase[b] + bb[b] + r;
        nlist[p] = i;
        spos[i] = p;
        stype_s[p] = t;
        deg_s[p] = dg;
    }
}

// row_start over sorted index space: block exclusive scan + one atomic block base.
__global__ __launch_bounds__(256) void row_scan(const int* __restrict__ deg_s,
                                                int* __restrict__ row_start,
                                                int* __restrict__ gcur, int N) {
    __shared__ int tmp[256];
    __shared__ int base;
    int i = blockIdx.x * 256 + threadIdx.x;
    int v = i < N ? deg_s[i] : 0;
    tmp[threadIdx.x] = v;
    __syncthreads();
    #pragma unroll
    for (int off = 1; off < 256; off <<= 1) {
        int t = threadIdx.x >= off ? tmp[threadIdx.x - off] : 0;
        __syncthreads();
        tmp[threadIdx.x] += t;
        __syncthreads();
    }
    if (threadIdx.x == 255) base = atomicAdd(gcur, tmp[255]);
    __syncthreads();
    if (i < N) row_start[i] = base + tmp[threadIdx.x] - v;
}

// ebuf entry: sps(17) | r(2)@17 | tm(8)@19 | st(2)@27
__global__ void scatter_kernel(const int* __restrict__ ei, const int* __restrict__ etype,
                               const int* __restrict__ etime, const int* __restrict__ spos,
                               const int* __restrict__ dbase,
                               const int* __restrict__ row_start, int* __restrict__ cursor,
                               unsigned* __restrict__ ebuf, int E) {
    int tb1 = dbase[64], tb2 = dbase[128], tb3 = dbase[192];
    int i = blockIdx.x * blockDim.x + threadIdx.x;
    int stride = gridDim.x * blockDim.x;
    for (int e = i; e < E; e += stride) {
        int sps = spos[ei[e]];
        int spt = spos[ei[E + e]];
        int st = (sps >= tb1) + (sps >= tb2) + (sps >= tb3);
        int pos = atomicAdd(&cursor[spt], 1);
        ebuf[row_start[spt] + pos] =
            (unsigned)sps | ((unsigned)etype[e] << 17) | ((unsigned)etime[e] << 19) | ((unsigned)st << 27);
    }
}

// Fused RTE tables -> combined fp8 table rtec8[(st*4+r)*240+tm][256B]
__global__ __launch_bounds__(128) void rte_tables(
    const float* __restrict__ rte_W, const float* __restrict__ rte_b,
    const float* __restrict__ Wk, const float* __restrict__ Wv,
    const float* __restrict__ rel_msg,
    unsigned char* __restrict__ rtec8) {
    int m = blockIdx.x, t = blockIdx.y, d = threadIdx.x;
    __shared__ float emb[128];
    __shared__ float sr[128];
    __shared__ float vr[128];
    int j2 = d & ~1;
    float div = expf((float)j2 * (-9.210340371976184f / 128.f));
    float ang = (float)m * div;
    emb[d] = ((d & 1) ? cosf(ang) : sinf(ang)) * 0.08838834764831845f;
    __syncthreads();
    float ro = rte_b[d];
    #pragma unroll 8
    for (int i = 0; i < 128; ++i) ro += emb[i] * rte_W[i * 128 + d];
    sr[d] = ro;
    __syncthreads();
    float ak = 0.f, av = 0.f;
    for (int i = 0; i < 128; ++i) {
        float rv = sr[i];
        ak += rv * Wk[(t * 128 + i) * 128 + d];
        av += rv * Wv[(t * 128 + i) * 128 + d];
    }
    unsigned char kb = (unsigned char)(fp8x2_enc(fminf(fmaxf(ak, -440.f), 440.f), 0.f) & 0xff);
    int koff = (d >> 3) * 16 + 8 + (d & 7);
    #pragma unroll
    for (int r = 0; r < NR; ++r)
        rtec8[(size_t)((t * 4 + r) * MAXLEN + m) * 256 + koff] = kb;
    vr[d] = av;
    __syncthreads();
    int h = d >> 4, dd = d & 15;
    int voff = (d >> 3) * 16 + (d & 7);
    for (int r = 0; r < NR; ++r) {
        float acc = 0.f;
        #pragma unroll
        for (int k = 0; k < 16; ++k)
            acc += vr[h * 16 + k] * rel_msg[((r * NH + h) * 16 + k) * 16 + dd];
        unsigned char vb = (unsigned char)(fp8x2_enc(fminf(fmaxf(acc, -440.f), 440.f), 0.f) & 0xff);
        rtec8[(size_t)((t * 4 + r) * MAXLEN + m) * 256 + voff] = vb;
    }
}

// Fold rel transforms into weights (true scale).
__global__ __launch_bounds__(256) void pack_w9(
    const float* __restrict__ Wk, const float* __restrict__ Wq,
    const float* __restrict__ Wv, const float* __restrict__ Wa,
    const float* __restrict__ bk, const float* __restrict__ bq,
    const float* __restrict__ bv, const float* __restrict__ ba,
    const float* __restrict__ rel_att, const float* __restrict__ rel_msg,
    const float* __restrict__ rel_pri,
    short* __restrict__ PW2, float* __restrict__ PB) {
    if (blockIdx.x >= 320) {
        int bidx = (blockIdx.x - 320) * 256 + threadIdx.x;
        int col = bidx & 127, t = (bidx >> 7) & 3, set = bidx >> 9;
        int h = col >> 4, kk = col & 15;
        float val;
        if (set == 0) val = bk[t * 128 + col];
        else if (set == 9) val = ba[t * 128 + col];
        else if (set <= 4) {
            int r = set - 1;
            float pri = rel_pri[r * NH + h] * 0.25f;
            float acc = 0.f;
            #pragma unroll
            for (int dp = 0; dp < 16; ++dp)
                acc += bq[t * 128 + h * 16 + dp] * rel_att[((r * NH + h) * 16 + kk) * 16 + dp];
            val = acc * pri;
        } else {
            int r = set - 5;
            float acc = 0.f;
            #pragma unroll
            for (int kp = 0; kp < 16; ++kp)
                acc += bv[t * 128 + h * 16 + kp] * rel_msg[((r * NH + h) * 16 + kp) * 16 + kk];
            val = acc;
        }
        PB[bidx] = val;
        return;
    }
    int idx = blockIdx.x * 256 + threadIdx.x;
    int lane = idx & 63;
    int ks = (idx >> 6) & 3;
    int ctg = (idx >> 8) & 7;
    int t = (idx >> 11) & 3;
    int set = idx >> 13;
    int col = ctg * 16 + (lane & 15);
    int k0 = ks * 32 + (lane >> 4) * 8;
    int h = col >> 4, kk = col & 15;
    unsigned short o[8];
    if (set == 0 || set == 9) {
        const float* W = (set == 0 ? Wk : Wa) + t * 16384;
        #pragma unroll
        for (int j = 0; j < 8; ++j) o[j] = f2bf(W[(k0 + j) * 128 + col]);
    } else if (set <= 4) {
        int r = set - 1;
        float pri = rel_pri[r * NH + h] * 0.25f;
        float Ar[16];
        #pragma unroll
        for (int dp = 0; dp < 16; ++dp)
            Ar[dp] = rel_att[((r * NH + h) * 16 + kk) * 16 + dp] * pri;
        #pragma unroll
        for (int j = 0; j < 8; ++j) {
            const float* wr = Wq + (size_t)(t * 128 + k0 + j) * 128 + h * 16;
            float acc = 0.f;
            #pragma unroll
            for (int dp = 0; dp < 16; ++dp) acc += wr[dp] * Ar[dp];
            o[j] = f2bf(acc);
        }
    } else {
        int r = set - 5;
        float Mc[16];
        #pragma unroll
        for (int kp = 0; kp < 16; ++kp)
            Mc[kp] = rel_msg[((r * NH + h) * 16 + kp) * 16 + kk];
        #pragma unroll
        for (int j = 0; j < 8; ++j) {
            const float* wr = Wv + (size_t)(t * 128 + k0 + j) * 128 + h * 16;
            float acc = 0.f;
            #pragma unroll
            for (int kp = 0; kp < 16; ++kp) acc += wr[kp] * Mc[kp];
            o[j] = f2bf(acc);
        }
    }
    uint4 pk;
    pk.x = (unsigned)o[0] | ((unsigned)o[1] << 16);
    pk.y = (unsigned)o[2] | ((unsigned)o[3] << 16);
    pk.z = (unsigned)o[4] | ((unsigned)o[5] << 16);
    pk.w = (unsigned)o[6] | ((unsigned)o[7] << 16);
    *reinterpret_cast<uint4*>(PW2 + (size_t)idx * 8) = pk;
}

#define S8 144
#define KST 144

// 32 sorted nodes/tile: MFMA GEMM, ALL 9 output sets fp8, double-buffered staging.
__global__ __launch_bounds__(256, 4) void kqv2(
    const float* __restrict__ x, const int* __restrict__ nlist_,
    const int* __restrict__ stype_s, const short* __restrict__ PW2,
    const float* __restrict__ PB,
    unsigned char* __restrict__ knvm8, unsigned char* __restrict__ qa8, int N) {
    __shared__ short af_l[2][4][64][8];
    __shared__ unsigned char obuf[2][32 * S8];
    __shared__ unsigned char kn_keep[32 * KST];
    __shared__ int st_l[32];
    const int tid = threadIdx.x;
    const int sp0 = blockIdx.x * 32;
    if (tid < 32) {
        int sp = sp0 + tid;
        st_l[tid] = stype_s[sp < N ? sp : N - 1];
    }
    {
        int i = tid >> 3;
        int d0 = (tid & 7) * 16;
        int sp = sp0 + i;
        int nid = nlist_[sp < N ? sp : N - 1];
        const float* xr = x + (size_t)nid * 128 + d0;
        float4 f0 = *reinterpret_cast<const float4*>(xr);
        float4 f1 = *reinterpret_cast<const float4*>(xr + 4);
        float4 f2 = *reinterpret_cast<const float4*>(xr + 8);
        float4 f3 = *reinterpret_cast<const float4*>(xr + 12);
        int m = i >> 4, rr = i & 15;
        int ks = d0 >> 5;
        int sub = (d0 >> 3) & 3;
        uint4 p0, p1;
        p0.x = pack2(f0.x, f0.y); p0.y = pack2(f0.z, f0.w);
        p0.z = pack2(f1.x, f1.y); p0.w = pack2(f1.z, f1.w);
        p1.x = pack2(f2.x, f2.y); p1.y = pack2(f2.z, f2.w);
        p1.z = pack2(f3.x, f3.y); p1.w = pack2(f3.z, f3.w);
        *reinterpret_cast<uint4*>(&af_l[m][ks][sub * 16 + rr][0]) = p0;
        *reinterpret_cast<uint4*>(&af_l[m][ks][(sub + 1) * 16 + rr][0]) = p1;
    }
    __syncthreads();

    const int lane = tid & 63, w = tid >> 6;
    const int col_l = lane & 15, rowg = lane >> 4;
    const int t0 = st_l[0], t1 = st_l[31];

    bf16x8 afr[2][4];
    #pragma unroll
    for (int m = 0; m < 2; ++m)
        #pragma unroll
        for (int ks = 0; ks < 4; ++ks)
            afr[m][ks] = *reinterpret_cast<const bf16x8*>(&af_l[m][ks][lane][0]);

    const int wi = tid >> 3, wseg = tid & 7;
    const int wsp = sp0 + wi;

    for (int set = 0; set < 9; ++set) {
        unsigned char* buf = &obuf[set & 1][0];
        for (int t = t0; t <= t1; ++t) {
            #pragma unroll
            for (int c = 0; c < 2; ++c) {
                int ctg = w + c * 4;
                bf16x8 pf[4];
                #pragma unroll
                for (int ks = 0; ks < 4; ++ks)
                    pf[ks] = *reinterpret_cast<const bf16x8*>(
                        PW2 + ((size_t)((((set * 4 + t) * 8 + ctg) * 4 + ks) * 64 + lane)) * 8);
                float bval = PB[(set * 4 + t) * 128 + ctg * 16 + col_l];
                #pragma unroll
                for (int m = 0; m < 2; ++m) {
                    f32x4 acc = {0.f, 0.f, 0.f, 0.f};
                    #pragma unroll
                    for (int ks = 0; ks < 4; ++ks)
                        acc = __builtin_amdgcn_mfma_f32_16x16x32_bf16(afr[m][ks], pf[ks], acc, 0, 0, 0);
                    float c0 = fminf(fmaxf(acc[0] + bval, -440.f), 440.f);
                    float c1 = fminf(fmaxf(acc[1] + bval, -440.f), 440.f);
                    float c2 = fminf(fmaxf(acc[2] + bval, -440.f), 440.f);
                    float c3 = fminf(fmaxf(acc[3] + bval, -440.f), 440.f);
                    unsigned pA = fp8x2_enc(c0, c1);
                    unsigned pB = fp8x2_enc(c2, c3);
                    unsigned char by[4];
                    by[0] = (unsigned char)(pA & 0xff);
                    by[1] = (unsigned char)((pA >> 8) & 0xff);
                    by[2] = (unsigned char)(pB & 0xff);
                    by[3] = (unsigned char)((pB >> 8) & 0xff);
                    #pragma unroll
                    for (int j = 0; j < 4; ++j) {
                        int i = m * 16 + rowg * 4 + j;
                        if (st_l[i] == t)
                            buf[i * S8 + ctg * 16 + col_l] = by[j];
                    }
                }
            }
        }
        __syncthreads();
        if (set == 0) {
            *reinterpret_cast<uint4*>(&kn_keep[wi * KST + wseg * 16]) =
                *reinterpret_cast<const uint4*>(&buf[wi * S8 + wseg * 16]);
        } else if (set <= 4) {
            if (wsp < N) {
                int r = set - 1;
                *reinterpret_cast<uint4*>(qa8 + (size_t)(wsp * 4 + r) * 128 + wseg * 16) =
                    *reinterpret_cast<const uint4*>(&buf[wi * S8 + wseg * 16]);
            }
        } else {
            if (wsp < N) {
                int r = set - 5;
                unsigned char* dst = knvm8 + (size_t)(wsp * 4 + r) * 256;
                #pragma unroll
                for (int cc = 0; cc < 2; ++cc) {
                    int c = wseg * 2 + cc;
                    uint2 vmc = *reinterpret_cast<const uint2*>(&buf[wi * S8 + c * 8]);
                    uint2 knc = *reinterpret_cast<const uint2*>(&kn_keep[wi * KST + c * 8]);
                    uint4 outv;
                    outv.x = vmc.x; outv.y = vmc.y; outv.z = knc.x; outv.w = knc.y;
                    *reinterpret_cast<uint4*>(dst + c * 16) = outv;
                }
            }
        }
    }
}

// One sorted node per 16 lanes (4 nodes/wave); 4-edge unroll = 8 gathers in flight.
__global__ __launch_bounds__(256) void fused_edge_attn(
    const unsigned* __restrict__ ebuf, const int* __restrict__ row_start,
    const int* __restrict__ deg_s,
    const unsigned char* __restrict__ knvm8, const unsigned char* __restrict__ rtec8,
    const unsigned char* __restrict__ qa8,
    unsigned short* __restrict__ aggr_bf, int N) {
    int sp = blockIdx.x * 16 + (threadIdx.x >> 4);
    int l16 = threadIdx.x & 15;
    if (sp >= N) return;
    uint4 q[4];
    #pragma unroll
    for (int r = 0; r < 4; ++r) {
        uint2 qv = *reinterpret_cast<const uint2*>(qa8 + (size_t)(sp * 4 + r) * 128 + l16 * 8);
        float f[8];
        fp8x4_dec(qv.x, f); fp8x4_dec(qv.y, f + 4);
        q[r].x = pack2(f[0], f[1]); q[r].y = pack2(f[2], f[3]);
        q[r].z = pack2(f[4], f[5]); q[r].w = pack2(f[6], f[7]);
    }
    int start = row_start[sp], cnt = deg_s[sp];
    float den = 0.f;
    float acc[8] = {0.f, 0.f, 0.f, 0.f, 0.f, 0.f, 0.f, 0.f};
    int i = 0;
    for (; i + 4 <= cnt; i += 4) {
        unsigned em[4];
        #pragma unroll
        for (int u = 0; u < 4; ++u) em[u] = ebuf[start + i + u];
        uint4 ga[4], gb[4];
        #pragma unroll
        for (int u = 0; u < 4; ++u) {
            int sps = em[u] & 0x1ffff, r = (em[u] >> 17) & 3;
            int tm = (em[u] >> 19) & 255, st = (em[u] >> 27) & 3;
            ga[u] = *reinterpret_cast<const uint4*>(knvm8 + (size_t)(sps * 4 + r) * 256 + l16 * 16);
            gb[u] = *reinterpret_cast<const uint4*>(rtec8 + (size_t)((st * 4 + r) * MAXLEN + tm) * 256 + l16 * 16);
        }
        #pragma unroll
        for (int u = 0; u < 4; ++u) {
            int r = (em[u] >> 17) & 3;
            float mf[8], kf[8], mr[8], kr[8];
            fp8x4_dec(ga[u].x, mf); fp8x4_dec(ga[u].y, mf + 4);
            fp8x4_dec(ga[u].z, kf); fp8x4_dec(ga[u].w, kf + 4);
            fp8x4_dec(gb[u].x, mr); fp8x4_dec(gb[u].y, mr + 4);
            fp8x4_dec(gb[u].z, kr); fp8x4_dec(gb[u].w, kr + 4);
            uint4 q0 = q[r];
            float p = (kf[0] + kr[0]) * bflo(q0.x) + (kf[1] + kr[1]) * bfhi(q0.x)
                    + (kf[2] + kr[2]) * bflo(q0.y) + (kf[3] + kr[3]) * bfhi(q0.y)
                    + (kf[4] + kr[4]) * bflo(q0.z) + (kf[5] + kr[5]) * bfhi(q0.z)
                    + (kf[6] + kr[6]) * bflo(q0.w) + (kf[7] + kr[7]) * bfhi(q0.w);
            p += __shfl_xor(p, 1);
            float w0 = __expf(p);
            den += w0;
            #pragma unroll
            for (int j = 0; j < 8; ++j)
                acc[j] += w0 * (mf[j] + mr[j]);
        }
    }
    for (; i < cnt; ++i) {
        unsigned e0 = ebuf[start + i];
        int sps0 = e0 & 0x1ffff, r0 = (e0 >> 17) & 3, tm0 = (e0 >> 19) & 255, st0 = (e0 >> 27) & 3;
        uint4 g1 = *reinterpret_cast<const uint4*>(knvm8 + (size_t)(sps0 * 4 + r0) * 256 + l16 * 16);
        uint4 g2 = *reinterpret_cast<const uint4*>(rtec8 + (size_t)((st0 * 4 + r0) * MAXLEN + tm0) * 256 + l16 * 16);
        float mf[8], kf[8], mr[8], kr[8];
        fp8x4_dec(g1.x, mf); fp8x4_dec(g1.y, mf + 4);
        fp8x4_dec(g1.z, kf); fp8x4_dec(g1.w, kf + 4);
        fp8x4_dec(g2.x, mr); fp8x4_dec(g2.y, mr + 4);
        fp8x4_dec(g2.z, kr); fp8x4_dec(g2.w, kr + 4);
        uint4 q0 = q[r0];
        float p = (kf[0] + kr[0]) * bflo(q0.x) + (kf[1] + kr[1]) * bfhi(q0.x)
                + (kf[2] + kr[2]) * bflo(q0.y) + (kf[3] + kr[3]) * bfhi(q0.y)
                + (kf[4] + kr[4]) * bflo(q0.z) + (kf[5] + kr[5]) * bfhi(q0.z)
                + (kf[6] + kr[6]) * bflo(q0.w) + (kf[7] + kr[7]) * bfhi(q0.w);
        p += __shfl_xor(p, 1);
        float w0 = __expf(p);
        den += w0;
        #pragma unroll
        for (int j = 0; j < 8; ++j)
            acc[j] += w0 * (mf[j] + mr[j]);
    }
    float inv = den > 0.f ? 1.f / den : 0.f;
    uint4 o;
    o.x = pack2(acc[0] * inv, acc[1] * inv);
    o.y = pack2(acc[2] * inv, acc[3] * inv);
    o.z = pack2(acc[4] * inv, acc[5] * inv);
    o.w = pack2(acc[6] * inv, acc[7] * inv);
    *reinterpret_cast<uint4*>(aggr_bf + (size_t)sp * 128 + l16 * 8) = o;
}

// 32 sorted nodes/tile: gelu(aggr bf16) -> MFMA Wa -> skip-blend -> LN -> scatter out
__global__ __launch_bounds__(256, 4) void update_sorted(
    const float* __restrict__ x, const int* __restrict__ nlist_,
    const int* __restrict__ stype_s, const short* __restrict__ PW2,
    const float* __restrict__ PB, const float* __restrict__ gamma,
    const float* __restrict__ beta, const float* __restrict__ skip,
    const unsigned short* __restrict__ aggr_bf, float* __restrict__ out, int N) {
    __shared__ short af_l[2][4][64][8];
    __shared__ float hs[32][128];
    __shared__ int st_l[32];
    __shared__ int nid_l[32];
    const int tid = threadIdx.x;
    const int sp0 = blockIdx.x * 32;
    if (tid < 32) {
        int sp = sp0 + tid;
        int spc = sp < N ? sp : N - 1;
        st_l[tid] = stype_s[spc];
        nid_l[tid] = nlist_[spc];
    }
    {
        int i = tid >> 3;
        int d0 = (tid & 7) * 16;
        int spc = sp0 + i < N ? sp0 + i : N - 1;
        const unsigned short* ar = aggr_bf + (size_t)spc * 128 + d0;
        uint4 v0 = *reinterpret_cast<const uint4*>(ar);
        uint4 v1 = *reinterpret_cast<const uint4*>(ar + 8);
        unsigned vv[8] = {v0.x, v0.y, v0.z, v0.w, v1.x, v1.y, v1.z, v1.w};
        float g[16];
        #pragma unroll
        for (int c = 0; c < 8; ++c) {
            float a0 = bflo(vv[c]), a1 = bfhi(vv[c]);
            g[c * 2 + 0] = 0.5f * a0 * (1.f + erff(a0 * 0.7071067811865476f));
            g[c * 2 + 1] = 0.5f * a1 * (1.f + erff(a1 * 0.7071067811865476f));
        }
        int m = i >> 4, rr = i & 15;
        int ks = d0 >> 5;
        int sub = (d0 >> 3) & 3;
        uint4 p0, p1;
        p0.x = pack2(g[0], g[1]);  p0.y = pack2(g[2], g[3]);
        p0.z = pack2(g[4], g[5]);  p0.w = pack2(g[6], g[7]);
        p1.x = pack2(g[8], g[9]);  p1.y = pack2(g[10], g[11]);
        p1.z = pack2(g[12], g[13]); p1.w = pack2(g[14], g[15]);
        *reinterpret_cast<uint4*>(&af_l[m][ks][sub * 16 + rr][0]) = p0;
        *reinterpret_cast<uint4*>(&af_l[m][ks][(sub + 1) * 16 + rr][0]) = p1;
    }
    __syncthreads();

    const int lane = tid & 63, w = tid >> 6;
    const int col_l = lane & 15, rowg = lane >> 4;
    const int t0 = st_l[0], t1 = st_l[31];

    bf16x8 afr[2][4];
    #pragma unroll
    for (int m = 0; m < 2; ++m)
        #pragma unroll
        for (int ks = 0; ks < 4; ++ks)
            afr[m][ks] = *reinterpret_cast<const bf16x8*>(&af_l[m][ks][lane][0]);

    for (int t = t0; t <= t1; ++t) {
        #pragma unroll
        for (int c = 0; c < 2; ++c) {
            int ctg = w + c * 4;
            bf16x8 pf[4];
            #pragma unroll
            for (int ks = 0; ks < 4; ++ks)
                pf[ks] = *reinterpret_cast<const bf16x8*>(
                    PW2 + ((size_t)((((9 * 4 + t) * 8 + ctg) * 4 + ks) * 64 + lane)) * 8);
            float bval = PB[(9 * 4 + t) * 128 + ctg * 16 + col_l];
            #pragma unroll
            for (int m = 0; m < 2; ++m) {
                f32x4 acc = {0.f, 0.f, 0.f, 0.f};
                #pragma unroll
                for (int ks = 0; ks < 4; ++ks)
                    acc = __builtin_amdgcn_mfma_f32_16x16x32_bf16(afr[m][ks], pf[ks], acc, 0, 0, 0);
                #pragma unroll
                for (int j = 0; j < 4; ++j) {
                    int i = m * 16 + rowg * 4 + j;
                    if (st_l[i] == t)
                        hs[i][ctg * 16 + col_l] = acc[j] + bval;
                }
            }
        }
    }
    __syncthreads();

    {
        int i = tid >> 3;
        int d0 = (tid & 7) * 16;
        int sp = sp0 + i;
        int nid = nid_l[i];
        int t = st_l[i];
        float alpha = 1.f / (1.f + expf(-skip[t]));
        const float* xr = x + (size_t)nid * 128 + d0;
        float hv[16];
        float s1 = 0.f, s2 = 0.f;
        #pragma unroll
        for (int c = 0; c < 4; ++c) {
            float4 xf = *reinterpret_cast<const float4*>(xr + c * 4);
            float4 tf;
            tf.x = hs[i][d0 + c * 4 + 0]; tf.y = hs[i][d0 + c * 4 + 1];
            tf.z = hs[i][d0 + c * 4 + 2]; tf.w = hs[i][d0 + c * 4 + 3];
            hv[c * 4 + 0] = tf.x * alpha + xf.x * (1.f - alpha);
            hv[c * 4 + 1] = tf.y * alpha + xf.y * (1.f - alpha);
            hv[c * 4 + 2] = tf.z * alpha + xf.z * (1.f - alpha);
            hv[c * 4 + 3] = tf.w * alpha + xf.w * (1.f - alpha);
            #pragma unroll
            for (int j = 0; j < 4; ++j) { s1 += hv[c * 4 + j]; s2 += hv[c * 4 + j] * hv[c * 4 + j]; }
        }
        #pragma unroll
        for (int off = 1; off < 8; off <<= 1) {
            s1 += __shfl_xor(s1, off);
            s2 += __shfl_xor(s2, off);
        }
        float mu = s1 * (1.f / 128.f);
        float var = s2 * (1.f / 128.f) - mu * mu;
        float inv = 1.f / sqrtf(var + 1e-5f);
        if (sp < N) {
            float* orow = out + (size_t)nid * 128 + d0;
            const float* gr = gamma + t * 128 + d0;
            const float* br = beta + t * 128 + d0;
            #pragma unroll
            for (int c = 0; c < 4; ++c) {
                float4 gf = *reinterpret_cast<const float4*>(gr + c * 4);
                float4 bf = *reinterpret_cast<const float4*>(br + c * 4);
                float4 of;
                of.x = (hv[c * 4 + 0] - mu) * inv * gf.x + bf.x;
                of.y = (hv[c * 4 + 1] - mu) * inv * gf.y + bf.y;
                of.z = (hv[c * 4 + 2] - mu) * inv * gf.z + bf.z;
                of.w = (hv[c * 4 + 3] - mu) * inv * gf.w + bf.w;
                *reinterpret_cast<float4*>(orow + c * 4) = of;
            }
        }
    }
}

extern "C" void kernel_launch(void* const* d_in, const int* in_sizes, int n_in,
                              void* d_out, int out_size, void* d_ws, size_t ws_size,
                              hipStream_t stream) {
    const float* node_inp = (const float*)d_in[0];
    const int*   node_type = (const int*)d_in[1];
    const int*   edge_index = (const int*)d_in[2];
    const int*   edge_type = (const int*)d_in[3];
    const int*   edge_time = (const int*)d_in[4];
    const float* Wk = (const float*)d_in[5];
    const float* bk = (const float*)d_in[6];
    const float* Wq = (const float*)d_in[7];
    const float* bq = (const float*)d_in[8];
    const float* Wv = (const float*)d_in[9];
    const float* bv = (const float*)d_in[10];
    const float* Wa = (const float*)d_in[11];
    const float* ba = (const float*)d_in[12];
    const float* gamma = (const float*)d_in[13];
    const float* beta = (const float*)d_in[14];
    const float* rel_pri = (const float*)d_in[15];
    const float* rel_att = (const float*)d_in[16];
    const float* rel_msg = (const float*)d_in[17];
    const float* skip = (const float*)d_in[18];
    const float* rte_W = (const float*)d_in[19];
    const float* rte_b = (const float*)d_in[20];

    int N = in_sizes[0] / 128;   // 50000
    int E = in_sizes[3];         // 600000

    char* base = (char*)d_ws;
    unsigned char* knvm8 = (unsigned char*)base;      base += (size_t)N * 4 * 256;
    unsigned char* qa8 = (unsigned char*)base;        base += (size_t)N * 4 * 128;
    unsigned short* aggr_bf = (unsigned short*)base;  base += (size_t)N * 128 * 2;
    unsigned char* rtec8 = (unsigned char*)base;      base += (size_t)NT * NR * MAXLEN * 256;
    short* PW2 = (short*)base;                base += (size_t)10 * NT * 128 * 128 * 2;
    float* PB = (float*)base;                 base += (size_t)10 * NT * 128 * 4;
    // contiguous zeroed int region: deg | cursor | dcnt | dcur | gcur(pad to 256)
    int* zbase = (int*)base;
    int* deg = zbase;                         // N
    int* cursor = zbase + N;                  // N
    int* dcnt = zbase + 2 * N;                // 256
    int* dcur = zbase + 2 * N + 256;          // 256
    int* gcur = zbase + 2 * N + 512;          // 256 (only [0] used)
    size_t zints = (size_t)2 * N + 768;
    base += zints * 4;
    int* deg_s = (int*)base;                  base += (size_t)N * 4;
    int* row_start = (int*)base;              base += (size_t)N * 4;
    int* nlist = (int*)base;                  base += (size_t)N * 4;
    int* spos = (int*)base;                   base += (size_t)N * 4;
    int* stype_s = (int*)base;                base += (size_t)N * 4;
    int* dbase = (int*)base;                  base += 256 * 4;
    base = (char*)(((size_t)base + 15) & ~(size_t)15);
    unsigned* ebuf = (unsigned*)base;         base += (size_t)E * 4;

    int ng = (N + 255) / 256;

    hipMemsetAsync(zbase, 0, zints * 4, stream);
    deg_kernel<<<1024, 256, 0, stream>>>(edge_index, deg, E);
    histA<<<ng, 256, 0, stream>>>(node_type, deg, dcnt, N);
    histB<<<1, 256, 0, stream>>>(dcnt, dbase);
    histC<<<ng, 256, 0, stream>>>(node_type, deg, dbase, dcur, nlist, spos, stype_s, deg_s, N);
    row_scan<<<ng, 256, 0, stream>>>(deg_s, row_start, gcur, N);
    scatter_kernel<<<1024, 256, 0, stream>>>(edge_index, edge_type, edge_time, spos, dbase,
                                             row_start, cursor, ebuf, E);
    dim3 gt(MAXLEN, NT);
    rte_tables<<<gt, 128, 0, stream>>>(rte_W, rte_b, Wk, Wv, rel_msg, rtec8);
    pack_w9<<<340, 256, 0, stream>>>(Wk, Wq, Wv, Wa, bk, bq, bv, ba,
                                     rel_att, rel_msg, rel_pri, PW2, PB);
    kqv2<<<(N + 31) / 32, 256, 0, stream>>>(node_inp, nlist, stype_s, PW2, PB,
                                            knvm8, qa8, N);
    fused_edge_attn<<<(N + 15) / 16, 256, 0, stream>>>(ebuf, row_start, deg_s,
                                                       knvm8, rtec8, qa8, aggr_bf, N);
    update_sorted<<<(N + 31) / 32, 256, 0, stream>>>(node_inp, nlist, stype_s, PW2, PB,
                                                     gamma, beta, skip, aggr_bf, (float*)d_out, N);
}